// Round 2
// baseline (647.667 us; speedup 1.0000x reference)
//
#include <hip/hip_runtime.h>
#include <hip/hip_bf16.h>

// NeuroMemory (all I/O float32): write-phase fast-weight update + 3 shared-KV
// attentions + fused (out_w, proj_w) tail:  out = sum_b O_b @ G_b^T + btot,
// G_b = pw_slice_b @ ow_b, btot = pb + bp_cat @ pw^T.
// Internals: bf16 MFMA GEMMs (f32 accum), f32 softmax/update.

using bf = __hip_bfloat16;
using short8v = __attribute__((ext_vector_type(8))) short;
using f32x4  = __attribute__((ext_vector_type(4))) float;

__device__ inline float bf2f(unsigned short s) {
    union { unsigned u; float f; } c; c.u = ((unsigned)s) << 16; return c.f;
}
__device__ inline unsigned short f2bu(float x) { // RNE f32->bf16 bits (finite inputs)
    union { float f; unsigned u; } c; c.f = x;
    unsigned r = c.u + 0x7FFF + ((c.u >> 16) & 1);
    return (unsigned short)(r >> 16);
}
__device__ inline void storeC(float* p, float v) { *p = v; }
__device__ inline void storeC(bf* p, float v) { *p = __float2bfloat16(v); }

// ---------------------------------------------------------------------------
// bf16 MFMA GEMM: C[M,N] = (ACC ? C : 0) + A[M,K] @ B[N,K]^T (+bias[N]).
// 128x128 tile, BK=64, 4 waves (2x2), LDS XOR-swizzle ((row&7)<<4 on bytes).
// ---------------------------------------------------------------------------
template <typename CT, bool ACC>
__global__ __launch_bounds__(256) void gemm_bt(
    const bf* __restrict__ A, int lda,
    const bf* __restrict__ B, int ldb,
    const float* __restrict__ bias,
    CT* __restrict__ C, int ldc,
    int M, int N, int K)
{
    __shared__ short As[128 * 64];
    __shared__ short Bs[128 * 64];
    const int nbn = N >> 7;
    const int bm = blockIdx.x / nbn, bn = blockIdx.x % nbn;
    const int t = threadIdx.x;
    const int w = t >> 6, lane = t & 63;
    const int wr = w >> 1, wc = w & 1;
    const int l16 = lane & 15, lhi = lane >> 4;

    f32x4 acc[4][4];
    #pragma unroll
    for (int i = 0; i < 4; ++i)
        #pragma unroll
        for (int j = 0; j < 4; ++j) { f32x4 z = {0.f, 0.f, 0.f, 0.f}; acc[i][j] = z; }

    const bf* Arow = A + (size_t)bm * 128 * lda;
    const bf* Brow = B + (size_t)bn * 128 * ldb;

    for (int k0 = 0; k0 < K; k0 += 64) {
        #pragma unroll
        for (int r = 0; r < 4; ++r) {
            int u = t + (r << 8);
            int row = u >> 3, c8 = u & 7;
            int slot = c8 ^ (row & 7);
            short8v av = *(const short8v*)(Arow + (size_t)row * lda + k0 + c8 * 8);
            short8v bv = *(const short8v*)(Brow + (size_t)row * ldb + k0 + c8 * 8);
            *(short8v*)&As[row * 64 + slot * 8] = av;
            *(short8v*)&Bs[row * 64 + slot * 8] = bv;
        }
        __syncthreads();
        #pragma unroll
        for (int kk = 0; kk < 2; ++kk) {
            short8v af[4], bfr[4];
            #pragma unroll
            for (int mt = 0; mt < 4; ++mt) {
                int row = wr * 64 + mt * 16 + l16;
                int c8 = kk * 4 + lhi;
                int slot = c8 ^ (row & 7);
                af[mt] = *(const short8v*)&As[row * 64 + slot * 8];
            }
            #pragma unroll
            for (int nt = 0; nt < 4; ++nt) {
                int row = wc * 64 + nt * 16 + l16;
                int c8 = kk * 4 + lhi;
                int slot = c8 ^ (row & 7);
                bfr[nt] = *(const short8v*)&Bs[row * 64 + slot * 8];
            }
            #pragma unroll
            for (int mt = 0; mt < 4; ++mt)
                #pragma unroll
                for (int nt = 0; nt < 4; ++nt)
                    acc[mt][nt] = __builtin_amdgcn_mfma_f32_16x16x32_bf16(
                        af[mt], bfr[nt], acc[mt][nt], 0, 0, 0);
        }
        __syncthreads();
    }
    #pragma unroll
    for (int mt = 0; mt < 4; ++mt)
        #pragma unroll
        for (int nt = 0; nt < 4; ++nt) {
            int col = bn * 128 + wc * 64 + nt * 16 + l16;
            float bv = bias ? bias[col] : 0.0f;
            #pragma unroll
            for (int j = 0; j < 4; ++j) {
                int rowg = bm * 128 + wr * 64 + mt * 16 + lhi * 4 + j;
                size_t idx = (size_t)rowg * ldc + col;
                float prev = ACC ? (float)C[idx] : 0.0f;
                storeC(&C[idx], prev + acc[mt][nt][j] + bv);
            }
        }
}

// ---------------------------------------------------------------------------
// MFMA attention, e/s banks: heads=16, d=64, M=256. Block = 4 waves, one
// (head, 64-row q-tile) each. P staged via XOR-swizzled LDS for the PV A-op.
// ---------------------------------------------------------------------------
__global__ __launch_bounds__(256) void attn_mfma(
    const bf* __restrict__ qh, const bf* __restrict__ kh,
    const bf* __restrict__ vhT, bf* __restrict__ O)
{
    __shared__ bf Ps[64 * 256];
    const int qt = blockIdx.x >> 4, head = blockIdx.x & 15;
    const int t = threadIdx.x, w = t >> 6, lane = t & 63;
    const int l16 = lane & 15, lhi = lane >> 4;
    const int qr0 = qt * 64 + w * 16;
    const float scale = 0.125f; // 1/sqrt(64)

    f32x4 sc[16];
    #pragma unroll
    for (int nt = 0; nt < 16; ++nt) { f32x4 z = {0.f, 0.f, 0.f, 0.f}; sc[nt] = z; }

    #pragma unroll
    for (int kk = 0; kk < 2; ++kk) {
        short8v a = *(const short8v*)(qh + (size_t)(qr0 + l16) * 1024 + head * 64 + kk * 32 + lhi * 8);
        #pragma unroll
        for (int nt = 0; nt < 16; ++nt) {
            short8v b = *(const short8v*)(kh + (size_t)(nt * 16 + l16) * 1024 + head * 64 + kk * 32 + lhi * 8);
            sc[nt] = __builtin_amdgcn_mfma_f32_16x16x32_bf16(a, b, sc[nt], 0, 0, 0);
        }
    }
    float mx[4], inv[4];
    #pragma unroll
    for (int j = 0; j < 4; ++j) {
        float m_ = -1e30f;
        #pragma unroll
        for (int nt = 0; nt < 16; ++nt) m_ = fmaxf(m_, sc[nt][j]);
        #pragma unroll
        for (int off = 8; off; off >>= 1) m_ = fmaxf(m_, __shfl_xor(m_, off));
        mx[j] = m_;
    }
    #pragma unroll
    for (int j = 0; j < 4; ++j) {
        float s_ = 0.f;
        #pragma unroll
        for (int nt = 0; nt < 16; ++nt) {
            float e = __expf((sc[nt][j] - mx[j]) * scale);
            sc[nt][j] = e; s_ += e;
        }
        #pragma unroll
        for (int off = 8; off; off >>= 1) s_ += __shfl_xor(s_, off);
        inv[j] = 1.0f / s_;
    }
    char* psb = (char*)Ps;
    #pragma unroll
    for (int nt = 0; nt < 16; ++nt)
        #pragma unroll
        for (int j = 0; j < 4; ++j) {
            int row = w * 16 + lhi * 4 + j;
            int col = nt * 16 + l16;
            int byte = row * 512 + ((col * 2) ^ ((row & 7) << 4));
            *(bf*)(psb + byte) = __float2bfloat16(sc[nt][j] * inv[j]);
        }
    __syncthreads();
    f32x4 oa[4];
    #pragma unroll
    for (int nt = 0; nt < 4; ++nt) { f32x4 z = {0.f, 0.f, 0.f, 0.f}; oa[nt] = z; }
    #pragma unroll
    for (int kk = 0; kk < 8; ++kk) {
        int row = w * 16 + l16;
        int cbyte = ((kk * 32 + lhi * 8) * 2) ^ ((row & 7) << 4);
        short8v a = *(const short8v*)(psb + row * 512 + cbyte);
        #pragma unroll
        for (int nt = 0; nt < 4; ++nt) {
            short8v b = *(const short8v*)(vhT + (size_t)(head * 64 + nt * 16 + l16) * 256 + kk * 32 + lhi * 8);
            oa[nt] = __builtin_amdgcn_mfma_f32_16x16x32_bf16(a, b, oa[nt], 0, 0, 0);
        }
    }
    #pragma unroll
    for (int nt = 0; nt < 4; ++nt)
        #pragma unroll
        for (int j = 0; j < 4; ++j)
            O[(size_t)(qt * 64 + w * 16 + lhi * 4 + j) * 1024 + head * 64 + nt * 16 + l16]
                = __float2bfloat16(oa[nt][j]);
}

// ---------------------------------------------------------------------------
// Working-memory attention: heads=8, d=128, M=10. 32 lanes per head.
// ---------------------------------------------------------------------------
__global__ __launch_bounds__(256) void attn_w(
    const bf* __restrict__ qh, const bf* __restrict__ khw,
    const bf* __restrict__ vhw, bf* __restrict__ O)
{
    const int bs = blockIdx.x;
    const int t = threadIdx.x;
    const int head = t >> 5;
    const int dg = head * 128 + (t & 31) * 4;

    ushort4 qv = *(const ushort4*)(qh + (size_t)bs * 1024 + dg);
    float q0 = bf2f(qv.x), q1 = bf2f(qv.y), q2 = bf2f(qv.z), q3 = bf2f(qv.w);
    float s[10];
    #pragma unroll
    for (int m = 0; m < 10; ++m) {
        ushort4 kv = *(const ushort4*)(khw + (size_t)m * 1024 + dg);
        float pr = q0 * bf2f(kv.x) + q1 * bf2f(kv.y) + q2 * bf2f(kv.z) + q3 * bf2f(kv.w);
        #pragma unroll
        for (int off = 16; off; off >>= 1) pr += __shfl_xor(pr, off);
        s[m] = pr * 0.08838834764831845f; // 1/sqrt(128)
    }
    float mx = s[0];
    #pragma unroll
    for (int m = 1; m < 10; ++m) mx = fmaxf(mx, s[m]);
    float pp[10], sum = 0.f;
    #pragma unroll
    for (int m = 0; m < 10; ++m) { pp[m] = __expf(s[m] - mx); sum += pp[m]; }
    float inv = 1.0f / sum;
    float o0 = 0, o1 = 0, o2 = 0, o3 = 0;
    #pragma unroll
    for (int m = 0; m < 10; ++m) {
        ushort4 vv = *(const ushort4*)(vhw + (size_t)m * 1024 + dg);
        o0 += pp[m] * bf2f(vv.x); o1 += pp[m] * bf2f(vv.y);
        o2 += pp[m] * bf2f(vv.z); o3 += pp[m] * bf2f(vv.w);
    }
    bf* op = O + (size_t)bs * 1024 + dg;
    op[0] = __float2bfloat16(o0 * inv); op[1] = __float2bfloat16(o1 * inv);
    op[2] = __float2bfloat16(o2 * inv); op[3] = __float2bfloat16(o3 * inv);
}

// --------------------------- small helper kernels ---------------------------

// f32 -> bf16 elementwise (n multiple of 4)
__global__ __launch_bounds__(256) void cvt_f2b(const float* __restrict__ in,
                                               bf* __restrict__ out, int n)
{
    int i = (blockIdx.x * 256 + threadIdx.x) * 4;
    if (i >= n) return;
    float4 v = *(const float4*)(in + i);
    ushort4 o;
    o.x = f2bu(v.x); o.y = f2bu(v.y); o.z = f2bu(v.z); o.w = f2bu(v.w);
    *(ushort4*)((unsigned short*)out + i) = o;
}

// 1024x1024 f32 -> bf16 transpose (outT); optional straight copy (outS).
__global__ __launch_bounds__(256) void transpose_cvt(
    const float* __restrict__ in, bf* __restrict__ outT, bf* __restrict__ outS)
{
    __shared__ unsigned short tile[64][65];
    int bx = blockIdx.x & 15, by = blockIdx.x >> 4;
    int r0 = by * 64, c0 = bx * 64;
    int tr = threadIdx.x >> 4, tc4 = (threadIdx.x & 15) * 4;
    #pragma unroll
    for (int i = 0; i < 4; ++i) {
        int r = tr + i * 16;
        float4 v = *(const float4*)(in + (size_t)(r0 + r) * 1024 + c0 + tc4);
        ushort4 o;
        o.x = f2bu(v.x); o.y = f2bu(v.y); o.z = f2bu(v.z); o.w = f2bu(v.w);
        tile[r][tc4 + 0] = o.x; tile[r][tc4 + 1] = o.y;
        tile[r][tc4 + 2] = o.z; tile[r][tc4 + 3] = o.w;
        if (outS) *(ushort4*)((unsigned short*)outS + (size_t)(r0 + r) * 1024 + c0 + tc4) = o;
    }
    __syncthreads();
    #pragma unroll
    for (int i = 0; i < 4; ++i) {
        int r = tr + i * 16;
        ushort4 v;
        v.x = tile[tc4 + 0][r]; v.y = tile[tc4 + 1][r];
        v.z = tile[tc4 + 2][r]; v.w = tile[tc4 + 3][r];
        *(ushort4*)((unsigned short*)outT + (size_t)(c0 + r) * 1024 + r0 + tc4) = v;
    }
}

// softmax rows of S1[1024,256], x0.1, write transposed wT[256,1024] (bf16)
__global__ __launch_bounds__(256) void write_softmax(const float* __restrict__ S1,
                                                     bf* __restrict__ wT)
{
    const int n = blockIdx.x, m = threadIdx.x;
    float s = S1[n * 256 + m];
    float mx = s;
    #pragma unroll
    for (int off = 32; off; off >>= 1) mx = fmaxf(mx, __shfl_xor(mx, off));
    __shared__ float red[4], red2[4];
    int w = threadIdx.x >> 6;
    if ((threadIdx.x & 63) == 0) red[w] = mx;
    __syncthreads();
    mx = fmaxf(fmaxf(red[0], red[1]), fmaxf(red[2], red[3]));
    float e = __expf(s - mx);
    float sm = e;
    #pragma unroll
    for (int off = 32; off; off >>= 1) sm += __shfl_xor(sm, off);
    if ((threadIdx.x & 63) == 0) red2[w] = sm;
    __syncthreads();
    sm = red2[0] + red2[1] + red2[2] + red2[3];
    wT[(size_t)m * 1024 + n] = __float2bfloat16(0.1f * e / sm);
}

// u[m] = mean_n w[n,m] (row-mean of wT)
__global__ __launch_bounds__(256) void usum_kern(const bf* __restrict__ wT, float* __restrict__ u)
{
    int w = threadIdx.x >> 6, lane = threadIdx.x & 63;
    int m = blockIdx.x * 4 + w;
    const bf* row = wT + (size_t)m * 1024;
    float s = 0.f;
    for (int i = lane; i < 1024; i += 64) s += __bfloat162float(row[i]);
    #pragma unroll
    for (int off = 32; off; off >>= 1) s += __shfl_xor(s, off);
    if (lane == 0) u[m] = s * (1.0f / 1024.0f);
}

// ek/ev = bank*(1-u[m]) + writesT[h,m]/NW  (epk/epv are f32; out bf16)
__global__ __launch_bounds__(256) void update_mem(
    const float* __restrict__ epk, const float* __restrict__ epv,
    const float* __restrict__ u, const float* __restrict__ writesT,
    bf* __restrict__ ek, bf* __restrict__ ev)
{
    int i = blockIdx.x * 256 + threadIdx.x; // 262144
    int m = i >> 10, h = i & 1023;
    float wr = writesT[(size_t)h * 256 + m] * (1.0f / 1024.0f);
    float f = 1.0f - u[m];
    ek[i] = __float2bfloat16(epk[i] * f + wr);
    ev[i] = __float2bfloat16(epv[i] * f + wr);
}

// bp[bank*1024+j] = out_b[j] + sum_h out_w[j,h] * in_b[2048+h]
__global__ __launch_bounds__(256) void bprime_kern(
    const float* ow0, const float* ob0, const float* ib0,
    const float* ow1, const float* ob1, const float* ib1,
    const float* ow2, const float* ob2, const float* ib2, float* bp)
{
    int g = blockIdx.x * 4 + (threadIdx.x >> 6); // 0..3071
    int lane = threadIdx.x & 63;
    int bank = g >> 10, j = g & 1023;
    const float* ow = bank == 0 ? ow0 : (bank == 1 ? ow1 : ow2);
    const float* ob = bank == 0 ? ob0 : (bank == 1 ? ob1 : ob2);
    const float* ib = bank == 0 ? ib0 : (bank == 1 ? ib1 : ib2);
    const float* wrow = ow + (size_t)j * 1024;
    const float* xx = ib + 2048;
    float acc = 0.f;
    #pragma unroll
    for (int cc = 0; cc < 4; ++cc) {
        float4 a = *(const float4*)(wrow + lane * 16 + cc * 4);
        float4 x = *(const float4*)(xx + lane * 16 + cc * 4);
        acc += a.x * x.x + a.y * x.y + a.z * x.z + a.w * x.w;
    }
    #pragma unroll
    for (int off = 32; off; off >>= 1) acc += __shfl_xor(acc, off);
    if (lane == 0) bp[g] = acc + ob[j];
}

// btot[j] = pb[j] + sum_{c<3072} bp[c] * pw[j*3072+c]
__global__ __launch_bounds__(256) void btot_kern(
    const float* __restrict__ bp, const float* __restrict__ pw,
    const float* __restrict__ pb, float* __restrict__ btot)
{
    int j = blockIdx.x * 4 + (threadIdx.x >> 6);
    int lane = threadIdx.x & 63;
    const float* row = pw + (size_t)j * 3072;
    float acc = 0.f;
    #pragma unroll
    for (int it = 0; it < 12; ++it) {
        int c = lane * 4 + it * 256;
        float4 a = *(const float4*)(row + c);
        float4 x = *(const float4*)(bp + c);
        acc += a.x * x.x + a.y * x.y + a.z * x.z + a.w * x.w;
    }
    #pragma unroll
    for (int off = 32; off; off >>= 1) acc += __shfl_xor(acc, off);
    if (lane == 0) btot[j] = acc + pb[j];
}

// working bank kh/vh: one wave per output dot (f32 inputs, bf16 out)
__global__ __launch_bounds__(256) void khvw_kern(
    const float* __restrict__ wm, const float* __restrict__ inw,
    const float* __restrict__ inb, bf* __restrict__ khw, bf* __restrict__ vhw)
{
    int o = blockIdx.x * 4 + (threadIdx.x >> 6); // 0..20479
    int lane = threadIdx.x & 63;
    int sel = o >= 10240;
    int o2 = o - sel * 10240;
    int m = o2 >> 10, c = o2 & 1023;
    const float* wrow = inw + (size_t)(1024 + sel * 1024 + c) * 1024;
    const float* xrow = wm + (size_t)m * 1024;
    float acc = 0.f;
    #pragma unroll
    for (int cc = 0; cc < 4; ++cc) {
        float4 a = *(const float4*)(wrow + lane * 16 + cc * 4);
        float4 x = *(const float4*)(xrow + lane * 16 + cc * 4);
        acc += a.x * x.x + a.y * x.y + a.z * x.z + a.w * x.w;
    }
    #pragma unroll
    for (int off = 32; off; off >>= 1) acc += __shfl_xor(acc, off);
    if (lane == 0) {
        float v = acc + (sel ? 0.f : inb[1024 + c]);
        (sel ? vhw : khw)[(size_t)m * 1024 + c] = __float2bfloat16(v);
    }
}

// ---------------------------------------------------------------------------
extern "C" void kernel_launch(void* const* d_in, const int* in_sizes, int n_in,
                              void* d_out, int out_size, void* d_ws, size_t ws_size,
                              hipStream_t stream)
{
    const float* q     = (const float*)d_in[0];
    const float* data  = (const float*)d_in[1];
    const float* epk   = (const float*)d_in[2];
    const float* epv   = (const float*)d_in[3];
    const float* smk   = (const float*)d_in[4];
    const float* smv   = (const float*)d_in[5];
    const float* wm    = (const float*)d_in[6];
    const float* inw_e = (const float*)d_in[7];  const float* inb_e = (const float*)d_in[8];
    const float* ow_e  = (const float*)d_in[9];  const float* ob_e  = (const float*)d_in[10];
    const float* inw_s = (const float*)d_in[11]; const float* inb_s = (const float*)d_in[12];
    const float* ow_s  = (const float*)d_in[13]; const float* ob_s  = (const float*)d_in[14];
    const float* inw_w = (const float*)d_in[15]; const float* inb_w = (const float*)d_in[16];
    const float* ow_w  = (const float*)d_in[17]; const float* ob_w  = (const float*)d_in[18];
    const float* pw    = (const float*)d_in[19]; const float* pb    = (const float*)d_in[20];
    float* out = (float*)d_out;

    char* p = (char*)d_ws;
    auto alloc = [&](size_t bytes) -> char* {
        char* r = p; p += (bytes + 255) & ~(size_t)255; return r;
    };
    float* S1    = (float*)alloc(1024 * 256 * 4);
    float* wrT   = (float*)alloc(1024 * 256 * 4);   // writes^T [1024h,256m]
    float* u     = (float*)alloc(256 * 4);
    float* bp    = (float*)alloc(3072 * 4);
    float* btot  = (float*)alloc(1024 * 4);
    bf* wT    = (bf*)alloc(256 * 1024 * 2);
    bf* datab = (bf*)alloc((size_t)1024 * 1024 * 2);
    bf* dT    = (bf*)alloc((size_t)1024 * 1024 * 2);
    bf* epkb  = (bf*)alloc(256 * 1024 * 2);
    bf* smkb  = (bf*)alloc(256 * 1024 * 2);
    bf* smvb  = (bf*)alloc(256 * 1024 * 2);
    bf* ek    = (bf*)alloc(256 * 1024 * 2);
    bf* ev    = (bf*)alloc(256 * 1024 * 2);
    bf* kh    = (bf*)alloc(256 * 1024 * 2);
    bf* vT    = (bf*)alloc((size_t)1024 * 256 * 2);
    bf* khw   = (bf*)alloc(10 * 1024 * 2);
    bf* vhw   = (bf*)alloc(10 * 1024 * 2);
    bf* qb    = (bf*)alloc((size_t)8192 * 1024 * 2);
    bf* inwbE = (bf*)alloc((size_t)3072 * 1024 * 2);
    bf* inwbS = (bf*)alloc((size_t)3072 * 1024 * 2);
    bf* inwbW = (bf*)alloc((size_t)3072 * 1024 * 2);
    bf* pwb   = (bf*)alloc((size_t)1024 * 3072 * 2);
    bf* owTb  = (bf*)alloc((size_t)1024 * 1024 * 2); // reused per bank
    bf* Gb    = (bf*)alloc((size_t)1024 * 1024 * 2); // reused per bank
    bf* qh    = (bf*)alloc((size_t)8192 * 1024 * 2);
    bf* Ob    = (bf*)alloc((size_t)8192 * 1024 * 2);
    if ((size_t)(p - (char*)d_ws) > ws_size) return;

    // ---- conversions (f32 -> bf16) ----
    cvt_f2b<<<8192, 256, 0, stream>>>(q, qb, 8192 * 1024);
    cvt_f2b<<<256, 256, 0, stream>>>(epk, epkb, 256 * 1024);
    cvt_f2b<<<256, 256, 0, stream>>>(smk, smkb, 256 * 1024);
    cvt_f2b<<<256, 256, 0, stream>>>(smv, smvb, 256 * 1024);
    cvt_f2b<<<3072, 256, 0, stream>>>(inw_e, inwbE, 3072 * 1024);
    cvt_f2b<<<3072, 256, 0, stream>>>(inw_s, inwbS, 3072 * 1024);
    cvt_f2b<<<3072, 256, 0, stream>>>(inw_w, inwbW, 3072 * 1024);
    cvt_f2b<<<3072, 256, 0, stream>>>(pw, pwb, 1024 * 3072);
    transpose_cvt<<<256, 256, 0, stream>>>(data, dT, datab);
    bprime_kern<<<768, 256, 0, stream>>>(ow_e, ob_e, inb_e, ow_s, ob_s, inb_s, ow_w, ob_w, inb_w, bp);
    btot_kern<<<256, 256, 0, stream>>>(bp, pw, pb, btot);

    // ---- write phase ----
    gemm_bt<float, false><<<16, 256, 0, stream>>>(datab, 1024, epkb, 1024, nullptr, S1, 256, 1024, 256, 1024);
    write_softmax<<<1024, 256, 0, stream>>>(S1, wT);
    usum_kern<<<64, 256, 0, stream>>>(wT, u);
    gemm_bt<float, false><<<16, 256, 0, stream>>>(dT, 1024, wT, 1024, nullptr, wrT, 256, 1024, 256, 1024);
    update_mem<<<1024, 256, 0, stream>>>(epk, epv, u, wrT, ek, ev);

    // ---- bank e ----
    gemm_bt<bf, false><<<16, 256, 0, stream>>>(ek, 1024, inwbE + (size_t)1024 * 1024, 1024, inb_e + 1024, kh, 1024, 256, 1024, 1024);
    gemm_bt<bf, false><<<16, 256, 0, stream>>>(inwbE + (size_t)2048 * 1024, 1024, ev, 1024, nullptr, vT, 256, 1024, 256, 1024);
    gemm_bt<bf, false><<<512, 256, 0, stream>>>(qb, 1024, inwbE, 1024, inb_e, qh, 1024, 8192, 1024, 1024);
    attn_mfma<<<2048, 256, 0, stream>>>(qh, kh, vT, Ob);
    transpose_cvt<<<256, 256, 0, stream>>>(ow_e, owTb, nullptr);
    gemm_bt<bf, false><<<64, 256, 0, stream>>>(pwb + 0, 3072, owTb, 1024, nullptr, Gb, 1024, 1024, 1024, 1024);
    gemm_bt<float, false><<<512, 256, 0, stream>>>(Ob, 1024, Gb, 1024, btot, out, 1024, 8192, 1024, 1024);

    // ---- bank s ----
    gemm_bt<bf, false><<<16, 256, 0, stream>>>(smkb, 1024, inwbS + (size_t)1024 * 1024, 1024, inb_s + 1024, kh, 1024, 256, 1024, 1024);
    gemm_bt<bf, false><<<16, 256, 0, stream>>>(inwbS + (size_t)2048 * 1024, 1024, smvb, 1024, nullptr, vT, 256, 1024, 256, 1024);
    gemm_bt<bf, false><<<512, 256, 0, stream>>>(qb, 1024, inwbS, 1024, inb_s, qh, 1024, 8192, 1024, 1024);
    attn_mfma<<<2048, 256, 0, stream>>>(qh, kh, vT, Ob);
    transpose_cvt<<<256, 256, 0, stream>>>(ow_s, owTb, nullptr);
    gemm_bt<bf, false><<<64, 256, 0, stream>>>(pwb + 1024, 3072, owTb, 1024, nullptr, Gb, 1024, 1024, 1024, 1024);
    gemm_bt<float, true><<<512, 256, 0, stream>>>(Ob, 1024, Gb, 1024, nullptr, out, 1024, 8192, 1024, 1024);

    // ---- bank w ----
    khvw_kern<<<5120, 256, 0, stream>>>(wm, inw_w, inb_w, khw, vhw);
    gemm_bt<bf, false><<<512, 256, 0, stream>>>(qb, 1024, inwbW, 1024, inb_w, qh, 1024, 8192, 1024, 1024);
    attn_w<<<8192, 256, 0, stream>>>(qh, khw, vhw, Ob);
    transpose_cvt<<<256, 256, 0, stream>>>(ow_w, owTb, nullptr);
    gemm_bt<bf, false><<<64, 256, 0, stream>>>(pwb + 2048, 3072, owTb, 1024, nullptr, Gb, 1024, 1024, 1024, 1024);
    gemm_bt<float, true><<<512, 256, 0, stream>>>(Ob, 1024, Gb, 1024, nullptr, out, 1024, 8192, 1024, 1024);
}

// Round 3
// 509.369 us; speedup vs baseline: 1.2715x; 1.2715x over previous
//
#include <hip/hip_runtime.h>
#include <hip/hip_bf16.h>

// NeuroMemory (f32 I/O): write-phase fast-weight update + 3 shared-KV attentions
// + fused (out_w, proj_w) tail: out = sum_b O_b @ G_b^T + btot, G_b = pw_b @ ow_b.
// bf16 MFMA GEMMs with global_load_lds staging (pre-swizzled source, linear LDS
// dest, XOR-swizzled reads); split-K (partials in d_out) for small GEMMs;
// LDS-staged attention.

using bf = __hip_bfloat16;
using short8v = __attribute__((ext_vector_type(8))) short;
using f32x4  = __attribute__((ext_vector_type(4))) float;

#define GLOAD_LDS16(g, l) __builtin_amdgcn_global_load_lds( \
    (const __attribute__((address_space(1))) void*)(g), \
    (__attribute__((address_space(3))) void*)(l), 16, 0, 0)

__device__ inline float bf2f(unsigned short s) {
    union { unsigned u; float f; } c; c.u = ((unsigned)s) << 16; return c.f;
}
__device__ inline unsigned short f2bu(float x) { // RNE f32->bf16 bits
    union { float f; unsigned u; } c; c.f = x;
    unsigned r = c.u + 0x7FFF + ((c.u >> 16) & 1);
    return (unsigned short)(r >> 16);
}
__device__ inline void storeC(float* p, float v) { *p = v; }
__device__ inline void storeC(bf* p, float v) { *p = __float2bfloat16(v); }

// ---------------------------------------------------------------------------
// bf16 MFMA GEMM: C = A[M,K] @ B[N,K]^T (+bias). 128x128 tile, BK=64, 4 waves.
// B staged via global_load_lds (16B, inverse-swizzled source, linear dest).
// A: same, or f32-in-global reg-staged+converted when AF32.
// SPLIT: gridDim.y K-chunks, write f32 partials C[chunk][M][N] (ldc==N).
// ---------------------------------------------------------------------------
template <typename CT, bool ACC, bool SPLIT, bool AF32>
__global__ __launch_bounds__(256) void gemm_bt(
    const void* __restrict__ Av, int lda,
    const bf* __restrict__ B, int ldb,
    const float* __restrict__ bias,
    CT* __restrict__ C, int ldc,
    int M, int N, int K)
{
    __shared__ short As[128 * 64];
    __shared__ short Bs[128 * 64];
    const int nbn = N >> 7;
    const int bm = blockIdx.x / nbn, bn = blockIdx.x % nbn;
    const int t = threadIdx.x;
    const int w = t >> 6, lane = t & 63;
    const int wr = w >> 1, wc = w & 1;
    const int l16 = lane & 15, lhi = lane >> 4;

    const int kc   = SPLIT ? (K / gridDim.y) : K;
    const int kbeg = SPLIT ? blockIdx.y * kc : 0;
    const int kend = kbeg + kc;

    f32x4 acc[4][4];
    #pragma unroll
    for (int i = 0; i < 4; ++i)
        #pragma unroll
        for (int j = 0; j < 4; ++j) { f32x4 z = {0.f, 0.f, 0.f, 0.f}; acc[i][j] = z; }

    const bf*    Arow = (const bf*)Av + (size_t)bm * 128 * lda;
    const float* Afrow = (const float*)Av + (size_t)bm * 128 * lda;
    const bf*    Brow = B + (size_t)bn * 128 * ldb;

    for (int k0 = kbeg; k0 < kend; k0 += 64) {
        // ---- stage B (and A unless AF32) via global_load_lds, src pre-swizzled
        #pragma unroll
        for (int j = 0; j < 4; ++j) {
            int ublk = w * 4 + j;
            int u = ublk * 64 + lane;
            int row = u >> 3, c8 = u & 7;
            int slot = c8 ^ (row & 7);
            GLOAD_LDS16(Brow + (size_t)row * ldb + k0 + slot * 8, &Bs[ublk * 512]);
            if (!AF32)
                GLOAD_LDS16(Arow + (size_t)row * lda + k0 + slot * 8, &As[ublk * 512]);
        }
        if (AF32) {
            #pragma unroll
            for (int r = 0; r < 4; ++r) {
                int u = t + (r << 8);
                int row = u >> 3, c8 = u & 7;
                const float* src = Afrow + (size_t)row * lda + k0 + c8 * 8;
                float4 v0 = *(const float4*)src;
                float4 v1 = *(const float4*)(src + 4);
                short8v sv;
                sv[0] = (short)f2bu(v0.x); sv[1] = (short)f2bu(v0.y);
                sv[2] = (short)f2bu(v0.z); sv[3] = (short)f2bu(v0.w);
                sv[4] = (short)f2bu(v1.x); sv[5] = (short)f2bu(v1.y);
                sv[6] = (short)f2bu(v1.z); sv[7] = (short)f2bu(v1.w);
                *(short8v*)&As[row * 64 + ((c8 ^ (row & 7)) * 8)] = sv;
            }
        }
        __syncthreads();
        #pragma unroll
        for (int kk = 0; kk < 2; ++kk) {
            short8v af[4], bfr[4];
            #pragma unroll
            for (int mt = 0; mt < 4; ++mt) {
                int row = wr * 64 + mt * 16 + l16;
                int slot = (kk * 4 + lhi) ^ (row & 7);
                af[mt] = *(const short8v*)&As[row * 64 + slot * 8];
            }
            #pragma unroll
            for (int nt = 0; nt < 4; ++nt) {
                int row = wc * 64 + nt * 16 + l16;
                int slot = (kk * 4 + lhi) ^ (row & 7);
                bfr[nt] = *(const short8v*)&Bs[row * 64 + slot * 8];
            }
            #pragma unroll
            for (int mt = 0; mt < 4; ++mt)
                #pragma unroll
                for (int nt = 0; nt < 4; ++nt)
                    acc[mt][nt] = __builtin_amdgcn_mfma_f32_16x16x32_bf16(
                        af[mt], bfr[nt], acc[mt][nt], 0, 0, 0);
        }
        __syncthreads();
    }
    #pragma unroll
    for (int mt = 0; mt < 4; ++mt)
        #pragma unroll
        for (int nt = 0; nt < 4; ++nt) {
            int col = bn * 128 + wc * 64 + nt * 16 + l16;
            float bv = (!SPLIT && bias) ? bias[col] : 0.0f;
            #pragma unroll
            for (int j = 0; j < 4; ++j) {
                int rowg = bm * 128 + wr * 64 + mt * 16 + lhi * 4 + j;
                if (SPLIT) {
                    ((float*)C)[(size_t)blockIdx.y * M * N + (size_t)rowg * ldc + col]
                        = acc[mt][nt][j];
                } else {
                    size_t idx = (size_t)rowg * ldc + col;
                    float prev = ACC ? (float)C[idx] : 0.0f;
                    storeC(&C[idx], prev + acc[mt][nt][j] + bv);
                }
            }
        }
}

// reduce split-K partials: out[row*ldo+col] = bias[col] + sum_s part[s][row*N+col]
template <typename CT, bool BIAS>
__global__ __launch_bounds__(256) void reduce_sk(
    const float* __restrict__ part, const float* __restrict__ bias,
    CT* __restrict__ outp, int MN, int N, int ldo, int SK)
{
    int i = (blockIdx.x * 256 + threadIdx.x) * 4;
    if (i >= MN) return;
    float4 s = *(const float4*)(part + i);
    for (int k = 1; k < SK; ++k) {
        float4 v = *(const float4*)(part + (size_t)k * MN + i);
        s.x += v.x; s.y += v.y; s.z += v.z; s.w += v.w;
    }
    int row = i / N, col = i - row * N;
    if (BIAS) {
        s.x += bias[col]; s.y += bias[col + 1];
        s.z += bias[col + 2]; s.w += bias[col + 3];
    }
    CT* o = outp + (size_t)row * ldo + col;
    storeC(o + 0, s.x); storeC(o + 1, s.y);
    storeC(o + 2, s.z); storeC(o + 3, s.w);
}

// ---------------------------------------------------------------------------
// Attention e/s banks: heads=16, d=64, M=256. 1024 blocks (64 q-tiles x 16
// heads), 512 threads = 8 waves, 16 q-rows/wave. K,V staged in LDS (64KB,
// XOR-swizzled via pre-swizzled global_load_lds source). P reuses the K
// region after a barrier, in two 128-wide halves (per-wave private rows).
// ---------------------------------------------------------------------------
__global__ __launch_bounds__(512) void attn_mfma2(
    const bf* __restrict__ qh, const bf* __restrict__ kh,
    const bf* __restrict__ vhT, bf* __restrict__ O)
{
    __shared__ short Ks[256 * 64];  // 32KB; reused as P after QK barrier
    __shared__ short Vs[64 * 256];  // 32KB
    const int qt = blockIdx.x >> 4, head = blockIdx.x & 15;
    const int t = threadIdx.x, w = t >> 6, lane = t & 63;
    const int l16 = lane & 15, lhi = lane >> 4;
    const float scale = 0.125f; // 1/sqrt(64)

    #pragma unroll
    for (int j = 0; j < 4; ++j) {
        int ublk = w * 4 + j;
        int u = ublk * 64 + lane;
        { int row = u >> 3, c8 = u & 7;
          int slot = c8 ^ (row & 7);
          GLOAD_LDS16(kh + (size_t)row * 1024 + head * 64 + slot * 8, &Ks[ublk * 512]); }
        { int row = u >> 5, c16 = u & 31;
          int slot = c16 ^ (row & 7);
          GLOAD_LDS16(vhT + (size_t)(head * 64 + row) * 256 + slot * 8, &Vs[ublk * 512]); }
    }
    const int qr = qt * 128 + w * 16 + l16;
    short8v aq0 = *(const short8v*)(qh + (size_t)qr * 1024 + head * 64 + lhi * 8);
    short8v aq1 = *(const short8v*)(qh + (size_t)qr * 1024 + head * 64 + 32 + lhi * 8);
    __syncthreads();

    f32x4 sc[16];
    #pragma unroll
    for (int nt = 0; nt < 16; ++nt) { f32x4 z = {0.f, 0.f, 0.f, 0.f}; sc[nt] = z; }
    #pragma unroll
    for (int nt = 0; nt < 16; ++nt) {
        int row = nt * 16 + l16;
        #pragma unroll
        for (int kk = 0; kk < 2; ++kk) {
            int slot = (kk * 4 + lhi) ^ (row & 7);
            short8v b = *(const short8v*)&Ks[row * 64 + slot * 8];
            sc[nt] = __builtin_amdgcn_mfma_f32_16x16x32_bf16(kk ? aq1 : aq0, b, sc[nt], 0, 0, 0);
        }
    }
    float inv[4];
    #pragma unroll
    for (int j = 0; j < 4; ++j) {
        float m_ = -1e30f;
        #pragma unroll
        for (int nt = 0; nt < 16; ++nt) m_ = fmaxf(m_, sc[nt][j]);
        #pragma unroll
        for (int off = 8; off; off >>= 1) m_ = fmaxf(m_, __shfl_xor(m_, off));
        float s_ = 0.f;
        #pragma unroll
        for (int nt = 0; nt < 16; ++nt) {
            float e = __expf((sc[nt][j] - m_) * scale);
            sc[nt][j] = e; s_ += e;
        }
        #pragma unroll
        for (int off = 8; off; off >>= 1) s_ += __shfl_xor(s_, off);
        inv[j] = 1.0f / s_;
    }
    __syncthreads(); // all waves done reading Ks -> reuse as P

    char* Pw = (char*)Ks + w * 4096; // 16 rows x 128 cols bf16, per-wave
    f32x4 oa[4];
    #pragma unroll
    for (int nt = 0; nt < 4; ++nt) { f32x4 z = {0.f, 0.f, 0.f, 0.f}; oa[nt] = z; }
    #pragma unroll
    for (int h = 0; h < 2; ++h) {
        #pragma unroll
        for (int nt = 0; nt < 8; ++nt) {
            int colL = nt * 16 + l16;
            #pragma unroll
            for (int j = 0; j < 4; ++j) {
                int row = lhi * 4 + j;
                *(short*)(Pw + row * 256 + ((colL * 2) ^ ((row & 7) << 4)))
                    = (short)f2bu(sc[h * 8 + nt][j] * inv[j]);
            }
        }
        #pragma unroll
        for (int kk = 0; kk < 4; ++kk) {
            short8v a = *(const short8v*)(Pw + l16 * 256 + (((kk * 32 + lhi * 8) * 2) ^ ((l16 & 7) << 4)));
            #pragma unroll
            for (int nt = 0; nt < 4; ++nt) {
                int row = nt * 16 + l16;
                int m = h * 128 + kk * 32 + lhi * 8;
                short8v b = *(const short8v*)((const char*)Vs + row * 512 + ((m * 2) ^ ((row & 7) << 4)));
                oa[nt] = __builtin_amdgcn_mfma_f32_16x16x32_bf16(a, b, oa[nt], 0, 0, 0);
            }
        }
    }
    #pragma unroll
    for (int nt = 0; nt < 4; ++nt)
        #pragma unroll
        for (int j = 0; j < 4; ++j)
            O[(size_t)(qt * 128 + w * 16 + lhi * 4 + j) * 1024 + head * 64 + nt * 16 + l16]
                = __float2bfloat16(oa[nt][j]);
}

// ---------------------------------------------------------------------------
// Working-memory attention: heads=8, d=128, M=10. 32 lanes per head.
// ---------------------------------------------------------------------------
__global__ __launch_bounds__(256) void attn_w(
    const bf* __restrict__ qh, const bf* __restrict__ khw,
    const bf* __restrict__ vhw, bf* __restrict__ O)
{
    const int bs = blockIdx.x;
    const int t = threadIdx.x;
    const int head = t >> 5;
    const int dg = head * 128 + (t & 31) * 4;

    ushort4 qv = *(const ushort4*)(qh + (size_t)bs * 1024 + dg);
    float q0 = bf2f(qv.x), q1 = bf2f(qv.y), q2 = bf2f(qv.z), q3 = bf2f(qv.w);
    float s[10];
    #pragma unroll
    for (int m = 0; m < 10; ++m) {
        ushort4 kv = *(const ushort4*)(khw + (size_t)m * 1024 + dg);
        float pr = q0 * bf2f(kv.x) + q1 * bf2f(kv.y) + q2 * bf2f(kv.z) + q3 * bf2f(kv.w);
        #pragma unroll
        for (int off = 16; off; off >>= 1) pr += __shfl_xor(pr, off);
        s[m] = pr * 0.08838834764831845f; // 1/sqrt(128)
    }
    float mx = s[0];
    #pragma unroll
    for (int m = 1; m < 10; ++m) mx = fmaxf(mx, s[m]);
    float pp[10], sum = 0.f;
    #pragma unroll
    for (int m = 0; m < 10; ++m) { pp[m] = __expf(s[m] - mx); sum += pp[m]; }
    float inv = 1.0f / sum;
    float o0 = 0, o1 = 0, o2 = 0, o3 = 0;
    #pragma unroll
    for (int m = 0; m < 10; ++m) {
        ushort4 vv = *(const ushort4*)(vhw + (size_t)m * 1024 + dg);
        o0 += pp[m] * bf2f(vv.x); o1 += pp[m] * bf2f(vv.y);
        o2 += pp[m] * bf2f(vv.z); o3 += pp[m] * bf2f(vv.w);
    }
    bf* op = O + (size_t)bs * 1024 + dg;
    op[0] = __float2bfloat16(o0 * inv); op[1] = __float2bfloat16(o1 * inv);
    op[2] = __float2bfloat16(o2 * inv); op[3] = __float2bfloat16(o3 * inv);
}

// --------------------------- small helper kernels ---------------------------

__global__ __launch_bounds__(256) void cvt_f2b(const float* __restrict__ in,
                                               bf* __restrict__ out, int n)
{
    int i = (blockIdx.x * 256 + threadIdx.x) * 4;
    if (i >= n) return;
    float4 v = *(const float4*)(in + i);
    ushort4 o;
    o.x = f2bu(v.x); o.y = f2bu(v.y); o.z = f2bu(v.z); o.w = f2bu(v.w);
    *(ushort4*)((unsigned short*)out + i) = o;
}

// 1024x1024 f32 -> bf16 transpose
__global__ __launch_bounds__(256) void transpose_cvt(
    const float* __restrict__ in, bf* __restrict__ outT)
{
    __shared__ unsigned short tile[64][65];
    int bx = blockIdx.x & 15, by = blockIdx.x >> 4;
    int r0 = by * 64, c0 = bx * 64;
    int tr = threadIdx.x >> 4, tc4 = (threadIdx.x & 15) * 4;
    #pragma unroll
    for (int i = 0; i < 4; ++i) {
        int r = tr + i * 16;
        float4 v = *(const float4*)(in + (size_t)(r0 + r) * 1024 + c0 + tc4);
        tile[r][tc4 + 0] = f2bu(v.x); tile[r][tc4 + 1] = f2bu(v.y);
        tile[r][tc4 + 2] = f2bu(v.z); tile[r][tc4 + 3] = f2bu(v.w);
    }
    __syncthreads();
    #pragma unroll
    for (int i = 0; i < 4; ++i) {
        int r = tr + i * 16;
        ushort4 v;
        v.x = tile[tc4 + 0][r]; v.y = tile[tc4 + 1][r];
        v.z = tile[tc4 + 2][r]; v.w = tile[tc4 + 3][r];
        *(ushort4*)((unsigned short*)outT + (size_t)(c0 + r) * 1024 + r0 + tc4) = v;
    }
}

// softmax rows of S1[1024,256], x0.1, write transposed wT[256,1024] (bf16)
__global__ __launch_bounds__(256) void write_softmax(const float* __restrict__ S1,
                                                     bf* __restrict__ wT)
{
    const int n = blockIdx.x, m = threadIdx.x;
    float s = S1[n * 256 + m];
    float mx = s;
    #pragma unroll
    for (int off = 32; off; off >>= 1) mx = fmaxf(mx, __shfl_xor(mx, off));
    __shared__ float red[4], red2[4];
    int w = threadIdx.x >> 6;
    if ((threadIdx.x & 63) == 0) red[w] = mx;
    __syncthreads();
    mx = fmaxf(fmaxf(red[0], red[1]), fmaxf(red[2], red[3]));
    float e = __expf(s - mx);
    float sm = e;
    #pragma unroll
    for (int off = 32; off; off >>= 1) sm += __shfl_xor(sm, off);
    if ((threadIdx.x & 63) == 0) red2[w] = sm;
    __syncthreads();
    sm = red2[0] + red2[1] + red2[2] + red2[3];
    wT[(size_t)m * 1024 + n] = __float2bfloat16(0.1f * e / sm);
}

__global__ __launch_bounds__(256) void usum_kern(const bf* __restrict__ wT, float* __restrict__ u)
{
    int w = threadIdx.x >> 6, lane = threadIdx.x & 63;
    int m = blockIdx.x * 4 + w;
    const bf* row = wT + (size_t)m * 1024;
    float s = 0.f;
    for (int i = lane; i < 1024; i += 64) s += __bfloat162float(row[i]);
    #pragma unroll
    for (int off = 32; off; off >>= 1) s += __shfl_xor(s, off);
    if (lane == 0) u[m] = s * (1.0f / 1024.0f);
}

__global__ __launch_bounds__(256) void update_mem(
    const float* __restrict__ epk, const float* __restrict__ epv,
    const float* __restrict__ u, const float* __restrict__ writesT,
    bf* __restrict__ ek, bf* __restrict__ ev)
{
    int i = blockIdx.x * 256 + threadIdx.x; // 262144
    int m = i >> 10, h = i & 1023;
    float wr = writesT[(size_t)h * 256 + m] * (1.0f / 1024.0f);
    float f = 1.0f - u[m];
    ek[i] = __float2bfloat16(epk[i] * f + wr);
    ev[i] = __float2bfloat16(epv[i] * f + wr);
}

// bp[bank*1024+j] = out_b[j] + sum_h out_w[j,h] * in_b[2048+h]
__global__ __launch_bounds__(256) void bprime_kern(
    const float* ow0, const float* ob0, const float* ib0,
    const float* ow1, const float* ob1, const float* ib1,
    const float* ow2, const float* ob2, const float* ib2, float* bp)
{
    int g = blockIdx.x * 4 + (threadIdx.x >> 6);
    int lane = threadIdx.x & 63;
    int bank = g >> 10, j = g & 1023;
    const float* ow = bank == 0 ? ow0 : (bank == 1 ? ow1 : ow2);
    const float* ob = bank == 0 ? ob0 : (bank == 1 ? ob1 : ob2);
    const float* ib = bank == 0 ? ib0 : (bank == 1 ? ib1 : ib2);
    const float* wrow = ow + (size_t)j * 1024;
    const float* xx = ib + 2048;
    float acc = 0.f;
    #pragma unroll
    for (int cc = 0; cc < 4; ++cc) {
        float4 a = *(const float4*)(wrow + lane * 16 + cc * 4);
        float4 x = *(const float4*)(xx + lane * 16 + cc * 4);
        acc += a.x * x.x + a.y * x.y + a.z * x.z + a.w * x.w;
    }
    #pragma unroll
    for (int off = 32; off; off >>= 1) acc += __shfl_xor(acc, off);
    if (lane == 0) bp[g] = acc + ob[j];
}

// btot[j] = pb[j] + sum_c bp[c] * pw[j*3072+c]
__global__ __launch_bounds__(256) void btot_kern(
    const float* __restrict__ bp, const float* __restrict__ pw,
    const float* __restrict__ pb, float* __restrict__ btot)
{
    int j = blockIdx.x * 4 + (threadIdx.x >> 6);
    int lane = threadIdx.x & 63;
    const float* row = pw + (size_t)j * 3072;
    float acc = 0.f;
    #pragma unroll
    for (int it = 0; it < 12; ++it) {
        int c = lane * 4 + it * 256;
        float4 a = *(const float4*)(row + c);
        float4 x = *(const float4*)(bp + c);
        acc += a.x * x.x + a.y * x.y + a.z * x.z + a.w * x.w;
    }
    #pragma unroll
    for (int off = 32; off; off >>= 1) acc += __shfl_xor(acc, off);
    if (lane == 0) btot[j] = acc + pb[j];
}

// working bank kh/vh
__global__ __launch_bounds__(256) void khvw_kern(
    const float* __restrict__ wm, const float* __restrict__ inw,
    const float* __restrict__ inb, bf* __restrict__ khw, bf* __restrict__ vhw)
{
    int o = blockIdx.x * 4 + (threadIdx.x >> 6); // 0..20479
    int lane = threadIdx.x & 63;
    int sel = o >= 10240;
    int o2 = o - sel * 10240;
    int m = o2 >> 10, c = o2 & 1023;
    const float* wrow = inw + (size_t)(1024 + sel * 1024 + c) * 1024;
    const float* xrow = wm + (size_t)m * 1024;
    float acc = 0.f;
    #pragma unroll
    for (int cc = 0; cc < 4; ++cc) {
        float4 a = *(const float4*)(wrow + lane * 16 + cc * 4);
        float4 x = *(const float4*)(xrow + lane * 16 + cc * 4);
        acc += a.x * x.x + a.y * x.y + a.z * x.z + a.w * x.w;
    }
    #pragma unroll
    for (int off = 32; off; off >>= 1) acc += __shfl_xor(acc, off);
    if (lane == 0) {
        float v = acc + (sel ? 0.f : inb[1024 + c]);
        (sel ? vhw : khw)[(size_t)m * 1024 + c] = __float2bfloat16(v);
    }
}

// ---------------------------------------------------------------------------
extern "C" void kernel_launch(void* const* d_in, const int* in_sizes, int n_in,
                              void* d_out, int out_size, void* d_ws, size_t ws_size,
                              hipStream_t stream)
{
    const float* q     = (const float*)d_in[0];
    const float* data  = (const float*)d_in[1];
    const float* epk   = (const float*)d_in[2];
    const float* epv   = (const float*)d_in[3];
    const float* smk   = (const float*)d_in[4];
    const float* smv   = (const float*)d_in[5];
    const float* wm    = (const float*)d_in[6];
    const float* inw_e = (const float*)d_in[7];  const float* inb_e = (const float*)d_in[8];
    const float* ow_e  = (const float*)d_in[9];  const float* ob_e  = (const float*)d_in[10];
    const float* inw_s = (const float*)d_in[11]; const float* inb_s = (const float*)d_in[12];
    const float* ow_s  = (const float*)d_in[13]; const float* ob_s  = (const float*)d_in[14];
    const float* inw_w = (const float*)d_in[15]; const float* inb_w = (const float*)d_in[16];
    const float* ow_w  = (const float*)d_in[17]; const float* ob_w  = (const float*)d_in[18];
    const float* pw    = (const float*)d_in[19]; const float* pb    = (const float*)d_in[20];
    float* out = (float*)d_out;
    float* part = (float*)d_out; // split-K partials live in d_out until phase 3

    char* p = (char*)d_ws;
    auto alloc = [&](size_t bytes) -> char* {
        char* r = p; p += (bytes + 255) & ~(size_t)255; return r;
    };
    float* S1   = (float*)alloc(1024 * 256 * 4);
    float* wrT  = (float*)alloc(1024 * 256 * 4);
    float* u    = (float*)alloc(256 * 4);
    float* bp   = (float*)alloc(3072 * 4);
    float* btot = (float*)alloc(1024 * 4);
    bf* wT    = (bf*)alloc(256 * 1024 * 2);
    bf* dT    = (bf*)alloc((size_t)1024 * 1024 * 2);
    bf* epkb  = (bf*)alloc(256 * 1024 * 2);
    bf* smkb  = (bf*)alloc(256 * 1024 * 2);
    bf* smvb  = (bf*)alloc(256 * 1024 * 2);
    bf* ek    = (bf*)alloc(256 * 1024 * 2);
    bf* ev    = (bf*)alloc(256 * 1024 * 2);
    bf* khE   = (bf*)alloc(256 * 1024 * 2);
    bf* khS   = (bf*)alloc(256 * 1024 * 2);
    bf* vTE   = (bf*)alloc((size_t)1024 * 256 * 2);
    bf* vTS   = (bf*)alloc((size_t)1024 * 256 * 2);
    bf* khw   = (bf*)alloc(10 * 1024 * 2);
    bf* vhw   = (bf*)alloc(10 * 1024 * 2);
    bf* inwbE = (bf*)alloc((size_t)3072 * 1024 * 2);
    bf* inwbS = (bf*)alloc((size_t)3072 * 1024 * 2);
    bf* inwbW = (bf*)alloc((size_t)3072 * 1024 * 2);
    bf* owT   = (bf*)alloc((size_t)1024 * 1024 * 2);
    bf* G3    = (bf*)alloc((size_t)3 * 1024 * 1024 * 2);
    bf* qh    = (bf*)alloc((size_t)8192 * 1024 * 2);
    bf* Ob    = (bf*)alloc((size_t)8192 * 1024 * 2);
    if ((size_t)(p - (char*)d_ws) > ws_size) return;

    // ---- phase 0: conversions & bias folds ----
    cvt_f2b<<<256, 256, 0, stream>>>(epk, epkb, 256 * 1024);
    cvt_f2b<<<256, 256, 0, stream>>>(smk, smkb, 256 * 1024);
    cvt_f2b<<<256, 256, 0, stream>>>(smv, smvb, 256 * 1024);
    cvt_f2b<<<3072, 256, 0, stream>>>(inw_e, inwbE, 3072 * 1024);
    cvt_f2b<<<3072, 256, 0, stream>>>(inw_s, inwbS, 3072 * 1024);
    cvt_f2b<<<3072, 256, 0, stream>>>(inw_w, inwbW, 3072 * 1024);
    transpose_cvt<<<256, 256, 0, stream>>>(data, dT);
    bprime_kern<<<768, 256, 0, stream>>>(ow_e, ob_e, inb_e, ow_s, ob_s, inb_s, ow_w, ob_w, inb_w, bp);
    btot_kern<<<256, 256, 0, stream>>>(bp, pw, pb, btot);

    // ---- phase 1: write phase (split-K partials in d_out) ----
    gemm_bt<float, false, true, true><<<dim3(16, 8), 256, 0, stream>>>(
        data, 1024, epkb, 1024, nullptr, part, 256, 1024, 256, 1024);
    reduce_sk<float, false><<<256, 256, 0, stream>>>(part, nullptr, S1, 1024 * 256, 256, 256, 8);
    write_softmax<<<1024, 256, 0, stream>>>(S1, wT);
    usum_kern<<<64, 256, 0, stream>>>(wT, u);
    gemm_bt<float, false, true, false><<<dim3(16, 8), 256, 0, stream>>>(
        dT, 1024, wT, 1024, nullptr, part, 256, 1024, 256, 1024);
    reduce_sk<float, false><<<256, 256, 0, stream>>>(part, nullptr, wrT, 1024 * 256, 256, 256, 8);
    update_mem<<<1024, 256, 0, stream>>>(epk, epv, u, wrT, ek, ev);

    // ---- phase 2: all pre-attention mid GEMMs (still using d_out partials) ----
    gemm_bt<float, false, true, false><<<dim3(16, 8), 256, 0, stream>>>(
        ek, 1024, inwbE + (size_t)1024 * 1024, 1024, nullptr, part, 1024, 256, 1024, 1024);
    reduce_sk<bf, true><<<256, 256, 0, stream>>>(part, inb_e + 1024, khE, 256 * 1024, 1024, 1024, 8);
    gemm_bt<float, false, true, false><<<dim3(16, 8), 256, 0, stream>>>(
        inwbE + (size_t)2048 * 1024, 1024, ev, 1024, nullptr, part, 256, 1024, 256, 1024);
    reduce_sk<bf, false><<<256, 256, 0, stream>>>(part, nullptr, vTE, 1024 * 256, 256, 256, 8);
    gemm_bt<float, false, true, false><<<dim3(16, 8), 256, 0, stream>>>(
        smkb, 1024, inwbS + (size_t)1024 * 1024, 1024, nullptr, part, 1024, 256, 1024, 1024);
    reduce_sk<bf, true><<<256, 256, 0, stream>>>(part, inb_s + 1024, khS, 256 * 1024, 1024, 1024, 8);
    gemm_bt<float, false, true, false><<<dim3(16, 8), 256, 0, stream>>>(
        inwbS + (size_t)2048 * 1024, 1024, smvb, 1024, nullptr, part, 256, 1024, 256, 1024);
    reduce_sk<bf, false><<<256, 256, 0, stream>>>(part, nullptr, vTS, 1024 * 256, 256, 256, 8);
    khvw_kern<<<5120, 256, 0, stream>>>(wm, inw_w, inb_w, khw, vhw);

    const float* ows[3] = {ow_e, ow_s, ow_w};
    for (int b = 0; b < 3; ++b) {
        transpose_cvt<<<256, 256, 0, stream>>>(ows[b], owT);
        gemm_bt<float, false, true, true><<<dim3(64, 8), 256, 0, stream>>>(
            pw + b * 1024, 3072, owT, 1024, nullptr, part, 1024, 1024, 1024, 1024);
        reduce_sk<bf, false><<<1024, 256, 0, stream>>>(
            part, nullptr, G3 + (size_t)b * 1024 * 1024, 1024 * 1024, 1024, 1024, 8);
    }

    // ---- phase 3: per-bank q-proj, attention, fused out GEMM ----
    // bank e (first write to out: bias=btot, no ACC)
    gemm_bt<bf, false, false, true><<<512, 256, 0, stream>>>(
        q, 1024, inwbE, 1024, inb_e, qh, 1024, 8192, 1024, 1024);
    attn_mfma2<<<1024, 512, 0, stream>>>(qh, khE, vTE, Ob);
    gemm_bt<float, false, false, false><<<512, 256, 0, stream>>>(
        Ob, 1024, G3 + 0, 1024, btot, out, 1024, 8192, 1024, 1024);
    // bank s
    gemm_bt<bf, false, false, true><<<512, 256, 0, stream>>>(
        q, 1024, inwbS, 1024, inb_s, qh, 1024, 8192, 1024, 1024);
    attn_mfma2<<<1024, 512, 0, stream>>>(qh, khS, vTS, Ob);
    gemm_bt<float, true, false, false><<<512, 256, 0, stream>>>(
        Ob, 1024, G3 + (size_t)1024 * 1024, 1024, nullptr, out, 1024, 8192, 1024, 1024);
    // bank w
    gemm_bt<bf, false, false, true><<<512, 256, 0, stream>>>(
        q, 1024, inwbW, 1024, inb_w, qh, 1024, 8192, 1024, 1024);
    attn_w<<<8192, 256, 0, stream>>>(qh, khw, vhw, Ob);
    gemm_bt<float, true, false, false><<<512, 256, 0, stream>>>(
        Ob, 1024, G3 + (size_t)2 * 1024 * 1024, 1024, nullptr, out, 1024, 8192, 1024, 1024);
}

// Round 4
// 423.295 us; speedup vs baseline: 1.5301x; 1.2033x over previous
//
#include <hip/hip_runtime.h>
#include <hip/hip_bf16.h>

// NeuroMemory (f32 I/O): write-phase fast-weight update + 3 shared-KV attentions
// + fused tail: out = Ocat[8192,3072] @ Gcat[1024,3072]^T + btot, G_b = pw_b @ ow_b.
// bf16 MFMA GEMMs, global_load_lds staging (pre-swizzled src, linear LDS dest,
// XOR-swizzled reads), XCD-aware block swizzle on big GEMMs, split-K partials in
// d_out for small GEMMs, qcat/qh_w aliased into d_out (dead until final GEMM).

using bf = __hip_bfloat16;
using short8v = __attribute__((ext_vector_type(8))) short;
using f32x4  = __attribute__((ext_vector_type(4))) float;

#define GLOAD_LDS16(g, l) __builtin_amdgcn_global_load_lds( \
    (const __attribute__((address_space(1))) void*)(g), \
    (__attribute__((address_space(3))) void*)(l), 16, 0, 0)

__device__ inline float bf2f(unsigned short s) {
    union { unsigned u; float f; } c; c.u = ((unsigned)s) << 16; return c.f;
}
__device__ inline unsigned short f2bu(float x) { // RNE f32->bf16 bits
    union { float f; unsigned u; } c; c.f = x;
    unsigned r = c.u + 0x7FFF + ((c.u >> 16) & 1);
    return (unsigned short)(r >> 16);
}
__device__ inline void storeC(float* p, float v) { *p = v; }
__device__ inline void storeC(bf* p, float v) { *p = __float2bfloat16(v); }

// ---------------------------------------------------------------------------
// bf16 MFMA GEMM: C = A[M,K] @ B[N,K]^T (+bias). 128x128 tile, BK=64, 4 waves.
// XSWZ: XCD-aware bijective remap (requires gridDim.x % 8 == 0).
// ---------------------------------------------------------------------------
template <typename CT, bool ACC, bool SPLIT, bool AF32, bool XSWZ>
__global__ __launch_bounds__(256) void gemm_bt(
    const void* __restrict__ Av, int lda,
    const bf* __restrict__ B, int ldb,
    const float* __restrict__ bias,
    CT* __restrict__ C, int ldc,
    int M, int N, int K)
{
    __shared__ short As[128 * 64];
    __shared__ short Bs[128 * 64];
    const int nbn = N >> 7;
    int bid = blockIdx.x;
    if (XSWZ) bid = (bid & 7) * (gridDim.x >> 3) + (bid >> 3);
    const int bm = bid / nbn, bn = bid % nbn;
    const int t = threadIdx.x;
    const int w = t >> 6, lane = t & 63;
    const int wr = w >> 1, wc = w & 1;
    const int l16 = lane & 15, lhi = lane >> 4;

    const int kc   = SPLIT ? (K / gridDim.y) : K;
    const int kbeg = SPLIT ? blockIdx.y * kc : 0;
    const int kend = kbeg + kc;

    f32x4 acc[4][4];
    #pragma unroll
    for (int i = 0; i < 4; ++i)
        #pragma unroll
        for (int j = 0; j < 4; ++j) { f32x4 z = {0.f, 0.f, 0.f, 0.f}; acc[i][j] = z; }

    const bf*    Arow  = (const bf*)Av + (size_t)bm * 128 * lda;
    const float* Afrow = (const float*)Av + (size_t)bm * 128 * lda;
    const bf*    Brow  = B + (size_t)bn * 128 * ldb;

    for (int k0 = kbeg; k0 < kend; k0 += 64) {
        #pragma unroll
        for (int j = 0; j < 4; ++j) {
            int ublk = w * 4 + j;
            int u = ublk * 64 + lane;
            int row = u >> 3, c8 = u & 7;
            int slot = c8 ^ (row & 7);
            GLOAD_LDS16(Brow + (size_t)row * ldb + k0 + slot * 8, &Bs[ublk * 512]);
            if (!AF32)
                GLOAD_LDS16(Arow + (size_t)row * lda + k0 + slot * 8, &As[ublk * 512]);
        }
        if (AF32) {
            #pragma unroll
            for (int r = 0; r < 4; ++r) {
                int u = t + (r << 8);
                int row = u >> 3, c8 = u & 7;
                const float* src = Afrow + (size_t)row * lda + k0 + c8 * 8;
                float4 v0 = *(const float4*)src;
                float4 v1 = *(const float4*)(src + 4);
                short8v sv;
                sv[0] = (short)f2bu(v0.x); sv[1] = (short)f2bu(v0.y);
                sv[2] = (short)f2bu(v0.z); sv[3] = (short)f2bu(v0.w);
                sv[4] = (short)f2bu(v1.x); sv[5] = (short)f2bu(v1.y);
                sv[6] = (short)f2bu(v1.z); sv[7] = (short)f2bu(v1.w);
                *(short8v*)&As[row * 64 + ((c8 ^ (row & 7)) * 8)] = sv;
            }
        }
        __syncthreads();
        #pragma unroll
        for (int kk = 0; kk < 2; ++kk) {
            short8v af[4], bfr[4];
            #pragma unroll
            for (int mt = 0; mt < 4; ++mt) {
                int row = wr * 64 + mt * 16 + l16;
                int slot = (kk * 4 + lhi) ^ (row & 7);
                af[mt] = *(const short8v*)&As[row * 64 + slot * 8];
            }
            #pragma unroll
            for (int nt = 0; nt < 4; ++nt) {
                int row = wc * 64 + nt * 16 + l16;
                int slot = (kk * 4 + lhi) ^ (row & 7);
                bfr[nt] = *(const short8v*)&Bs[row * 64 + slot * 8];
            }
            #pragma unroll
            for (int mt = 0; mt < 4; ++mt)
                #pragma unroll
                for (int nt = 0; nt < 4; ++nt)
                    acc[mt][nt] = __builtin_amdgcn_mfma_f32_16x16x32_bf16(
                        af[mt], bfr[nt], acc[mt][nt], 0, 0, 0);
        }
        __syncthreads();
    }
    #pragma unroll
    for (int mt = 0; mt < 4; ++mt)
        #pragma unroll
        for (int nt = 0; nt < 4; ++nt) {
            int col = bn * 128 + wc * 64 + nt * 16 + l16;
            float bv = (!SPLIT && bias) ? bias[col] : 0.0f;
            #pragma unroll
            for (int j = 0; j < 4; ++j) {
                int rowg = bm * 128 + wr * 64 + mt * 16 + lhi * 4 + j;
                if (SPLIT) {
                    ((float*)C)[(size_t)blockIdx.y * M * N + (size_t)rowg * ldc + col]
                        = acc[mt][nt][j];
                } else {
                    size_t idx = (size_t)rowg * ldc + col;
                    float prev = ACC ? (float)C[idx] : 0.0f;
                    storeC(&C[idx], prev + acc[mt][nt][j] + bv);
                }
            }
        }
}

// reduce split-K partials: out[row*ldo+col] = bias[col] + sum_s part[s][row*N+col]
template <typename CT, bool BIAS>
__global__ __launch_bounds__(256) void reduce_sk(
    const float* __restrict__ part, const float* __restrict__ bias,
    CT* __restrict__ outp, int MN, int N, int ldo, int SK)
{
    int i = (blockIdx.x * 256 + threadIdx.x) * 4;
    if (i >= MN) return;
    float4 s = *(const float4*)(part + i);
    for (int k = 1; k < SK; ++k) {
        float4 v = *(const float4*)(part + (size_t)k * MN + i);
        s.x += v.x; s.y += v.y; s.z += v.z; s.w += v.w;
    }
    int row = i / N, col = i - row * N;
    if (BIAS) {
        s.x += bias[col]; s.y += bias[col + 1];
        s.z += bias[col + 2]; s.w += bias[col + 3];
    }
    CT* o = outp + (size_t)row * ldo + col;
    storeC(o + 0, s.x); storeC(o + 1, s.y);
    storeC(o + 2, s.z); storeC(o + 3, s.w);
}

// ---------------------------------------------------------------------------
// Attention e/s banks: heads=16, d=64, M=256. 1024 blocks x 512 thr (8 waves,
// 16 q-rows each). K,V staged in LDS (swizzled via pre-swizzled gload src).
// P reuses the K region after a barrier, two 128-wide halves.
// ---------------------------------------------------------------------------
__global__ __launch_bounds__(512) void attn_mfma2(
    const bf* __restrict__ qh, int ldq, const bf* __restrict__ kh,
    const bf* __restrict__ vhT, bf* __restrict__ O, int ldo)
{
    __shared__ short Ks[256 * 64];  // 32KB; reused as P after QK barrier
    __shared__ short Vs[64 * 256];  // 32KB
    const int qt = blockIdx.x >> 4, head = blockIdx.x & 15;
    const int t = threadIdx.x, w = t >> 6, lane = t & 63;
    const int l16 = lane & 15, lhi = lane >> 4;
    const float scale = 0.125f; // 1/sqrt(64)

    #pragma unroll
    for (int j = 0; j < 4; ++j) {
        int ublk = w * 4 + j;
        int u = ublk * 64 + lane;
        { int row = u >> 3, c8 = u & 7;
          int slot = c8 ^ (row & 7);
          GLOAD_LDS16(kh + (size_t)row * 1024 + head * 64 + slot * 8, &Ks[ublk * 512]); }
        { int row = u >> 5, c16 = u & 31;
          int slot = c16 ^ (row & 7);
          GLOAD_LDS16(vhT + (size_t)(head * 64 + row) * 256 + slot * 8, &Vs[ublk * 512]); }
    }
    const int qr = qt * 128 + w * 16 + l16;
    short8v aq0 = *(const short8v*)(qh + (size_t)qr * ldq + head * 64 + lhi * 8);
    short8v aq1 = *(const short8v*)(qh + (size_t)qr * ldq + head * 64 + 32 + lhi * 8);
    __syncthreads();

    f32x4 sc[16];
    #pragma unroll
    for (int nt = 0; nt < 16; ++nt) { f32x4 z = {0.f, 0.f, 0.f, 0.f}; sc[nt] = z; }
    #pragma unroll
    for (int nt = 0; nt < 16; ++nt) {
        int row = nt * 16 + l16;
        #pragma unroll
        for (int kk = 0; kk < 2; ++kk) {
            int slot = (kk * 4 + lhi) ^ (row & 7);
            short8v b = *(const short8v*)&Ks[row * 64 + slot * 8];
            sc[nt] = __builtin_amdgcn_mfma_f32_16x16x32_bf16(kk ? aq1 : aq0, b, sc[nt], 0, 0, 0);
        }
    }
    float inv[4];
    #pragma unroll
    for (int j = 0; j < 4; ++j) {
        float m_ = -1e30f;
        #pragma unroll
        for (int nt = 0; nt < 16; ++nt) m_ = fmaxf(m_, sc[nt][j]);
        #pragma unroll
        for (int off = 8; off; off >>= 1) m_ = fmaxf(m_, __shfl_xor(m_, off));
        float s_ = 0.f;
        #pragma unroll
        for (int nt = 0; nt < 16; ++nt) {
            float e = __expf((sc[nt][j] - m_) * scale);
            sc[nt][j] = e; s_ += e;
        }
        #pragma unroll
        for (int off = 8; off; off >>= 1) s_ += __shfl_xor(s_, off);
        inv[j] = 1.0f / s_;
    }
    __syncthreads(); // all waves done reading Ks -> reuse as P

    char* Pw = (char*)Ks + w * 4096; // 16 rows x 128 cols bf16, per-wave
    f32x4 oa[4];
    #pragma unroll
    for (int nt = 0; nt < 4; ++nt) { f32x4 z = {0.f, 0.f, 0.f, 0.f}; oa[nt] = z; }
    #pragma unroll
    for (int h = 0; h < 2; ++h) {
        #pragma unroll
        for (int nt = 0; nt < 8; ++nt) {
            int colL = nt * 16 + l16;
            #pragma unroll
            for (int j = 0; j < 4; ++j) {
                int row = lhi * 4 + j;
                *(short*)(Pw + row * 256 + ((colL * 2) ^ ((row & 7) << 4)))
                    = (short)f2bu(sc[h * 8 + nt][j] * inv[j]);
            }
        }
        #pragma unroll
        for (int kk = 0; kk < 4; ++kk) {
            short8v a = *(const short8v*)(Pw + l16 * 256 + (((kk * 32 + lhi * 8) * 2) ^ ((l16 & 7) << 4)));
            #pragma unroll
            for (int nt = 0; nt < 4; ++nt) {
                int row = nt * 16 + l16;
                int m = h * 128 + kk * 32 + lhi * 8;
                short8v b = *(const short8v*)((const char*)Vs + row * 512 + ((m * 2) ^ ((row & 7) << 4)));
                oa[nt] = __builtin_amdgcn_mfma_f32_16x16x32_bf16(a, b, oa[nt], 0, 0, 0);
            }
        }
    }
    #pragma unroll
    for (int nt = 0; nt < 4; ++nt)
        #pragma unroll
        for (int j = 0; j < 4; ++j)
            O[(size_t)(qt * 128 + w * 16 + lhi * 4 + j) * ldo + head * 64 + nt * 16 + l16]
                = __float2bfloat16(oa[nt][j]);
}

// ---------------------------------------------------------------------------
// Working-memory attention: heads=8, d=128, M=10. 32 lanes per head.
// ---------------------------------------------------------------------------
__global__ __launch_bounds__(256) void attn_w(
    const bf* __restrict__ qh, int ldq, const bf* __restrict__ khw,
    const bf* __restrict__ vhw, bf* __restrict__ O, int ldo)
{
    const int bs = blockIdx.x;
    const int t = threadIdx.x;
    const int head = t >> 5;
    const int dg = head * 128 + (t & 31) * 4;

    ushort4 qv = *(const ushort4*)(qh + (size_t)bs * ldq + dg);
    float q0 = bf2f(qv.x), q1 = bf2f(qv.y), q2 = bf2f(qv.z), q3 = bf2f(qv.w);
    float s[10];
    #pragma unroll
    for (int m = 0; m < 10; ++m) {
        ushort4 kv = *(const ushort4*)(khw + (size_t)m * 1024 + dg);
        float pr = q0 * bf2f(kv.x) + q1 * bf2f(kv.y) + q2 * bf2f(kv.z) + q3 * bf2f(kv.w);
        #pragma unroll
        for (int off = 16; off; off >>= 1) pr += __shfl_xor(pr, off);
        s[m] = pr * 0.08838834764831845f; // 1/sqrt(128)
    }
    float mx = s[0];
    #pragma unroll
    for (int m = 1; m < 10; ++m) mx = fmaxf(mx, s[m]);
    float pp[10], sum = 0.f;
    #pragma unroll
    for (int m = 0; m < 10; ++m) { pp[m] = __expf(s[m] - mx); sum += pp[m]; }
    float inv = 1.0f / sum;
    float o0 = 0, o1 = 0, o2 = 0, o3 = 0;
    #pragma unroll
    for (int m = 0; m < 10; ++m) {
        ushort4 vv = *(const ushort4*)(vhw + (size_t)m * 1024 + dg);
        o0 += pp[m] * bf2f(vv.x); o1 += pp[m] * bf2f(vv.y);
        o2 += pp[m] * bf2f(vv.z); o3 += pp[m] * bf2f(vv.w);
    }
    bf* op = O + (size_t)bs * ldo + dg;
    op[0] = __float2bfloat16(o0 * inv); op[1] = __float2bfloat16(o1 * inv);
    op[2] = __float2bfloat16(o2 * inv); op[3] = __float2bfloat16(o3 * inv);
}

// --------------------------- small helper kernels ---------------------------

__global__ __launch_bounds__(256) void cvt_f2b(const float* __restrict__ in,
                                               bf* __restrict__ out, int n)
{
    int i = (blockIdx.x * 256 + threadIdx.x) * 4;
    if (i >= n) return;
    float4 v = *(const float4*)(in + i);
    ushort4 o;
    o.x = f2bu(v.x); o.y = f2bu(v.y); o.z = f2bu(v.z); o.w = f2bu(v.w);
    *(ushort4*)((unsigned short*)out + i) = o;
}

// 1024x1024 f32 -> bf16 transpose
__global__ __launch_bounds__(256) void transpose_cvt(
    const float* __restrict__ in, bf* __restrict__ outT)
{
    __shared__ unsigned short tile[64][65];
    int bx = blockIdx.x & 15, by = blockIdx.x >> 4;
    int r0 = by * 64, c0 = bx * 64;
    int tr = threadIdx.x >> 4, tc4 = (threadIdx.x & 15) * 4;
    #pragma unroll
    for (int i = 0; i < 4; ++i) {
        int r = tr + i * 16;
        float4 v = *(const float4*)(in + (size_t)(r0 + r) * 1024 + c0 + tc4);
        tile[r][tc4 + 0] = f2bu(v.x); tile[r][tc4 + 1] = f2bu(v.y);
        tile[r][tc4 + 2] = f2bu(v.z); tile[r][tc4 + 3] = f2bu(v.w);
    }
    __syncthreads();
    #pragma unroll
    for (int i = 0; i < 4; ++i) {
        int r = tr + i * 16;
        ushort4 v;
        v.x = tile[tc4 + 0][r]; v.y = tile[tc4 + 1][r];
        v.z = tile[tc4 + 2][r]; v.w = tile[tc4 + 3][r];
        *(ushort4*)((unsigned short*)outT + (size_t)(c0 + r) * 1024 + r0 + tc4) = v;
    }
}

// softmax rows of S1[1024,256], x0.1, write transposed wT[256,1024] (bf16)
__global__ __launch_bounds__(256) void write_softmax(const float* __restrict__ S1,
                                                     bf* __restrict__ wT)
{
    const int n = blockIdx.x, m = threadIdx.x;
    float s = S1[n * 256 + m];
    float mx = s;
    #pragma unroll
    for (int off = 32; off; off >>= 1) mx = fmaxf(mx, __shfl_xor(mx, off));
    __shared__ float red[4], red2[4];
    int w = threadIdx.x >> 6;
    if ((threadIdx.x & 63) == 0) red[w] = mx;
    __syncthreads();
    mx = fmaxf(fmaxf(red[0], red[1]), fmaxf(red[2], red[3]));
    float e = __expf(s - mx);
    float sm = e;
    #pragma unroll
    for (int off = 32; off; off >>= 1) sm += __shfl_xor(sm, off);
    if ((threadIdx.x & 63) == 0) red2[w] = sm;
    __syncthreads();
    sm = red2[0] + red2[1] + red2[2] + red2[3];
    wT[(size_t)m * 1024 + n] = __float2bfloat16(0.1f * e / sm);
}

__global__ __launch_bounds__(256) void usum_kern(const bf* __restrict__ wT, float* __restrict__ u)
{
    int w = threadIdx.x >> 6, lane = threadIdx.x & 63;
    int m = blockIdx.x * 4 + w;
    const bf* row = wT + (size_t)m * 1024;
    float s = 0.f;
    for (int i = lane; i < 1024; i += 64) s += __bfloat162float(row[i]);
    #pragma unroll
    for (int off = 32; off; off >>= 1) s += __shfl_xor(s, off);
    if (lane == 0) u[m] = s * (1.0f / 1024.0f);
}

__global__ __launch_bounds__(256) void update_mem(
    const float* __restrict__ epk, const float* __restrict__ epv,
    const float* __restrict__ u, const float* __restrict__ writesT,
    bf* __restrict__ ek, bf* __restrict__ ev)
{
    int i = blockIdx.x * 256 + threadIdx.x; // 262144
    int m = i >> 10, h = i & 1023;
    float wr = writesT[(size_t)h * 256 + m] * (1.0f / 1024.0f);
    float f = 1.0f - u[m];
    ek[i] = __float2bfloat16(epk[i] * f + wr);
    ev[i] = __float2bfloat16(epv[i] * f + wr);
}

// bp[bank*1024+j] = out_b[j] + sum_h out_w[j,h] * in_b[2048+h]
__global__ __launch_bounds__(256) void bprime_kern(
    const float* ow0, const float* ob0, const float* ib0,
    const float* ow1, const float* ob1, const float* ib1,
    const float* ow2, const float* ob2, const float* ib2, float* bp)
{
    int g = blockIdx.x * 4 + (threadIdx.x >> 6);
    int lane = threadIdx.x & 63;
    int bank = g >> 10, j = g & 1023;
    const float* ow = bank == 0 ? ow0 : (bank == 1 ? ow1 : ow2);
    const float* ob = bank == 0 ? ob0 : (bank == 1 ? ob1 : ob2);
    const float* ib = bank == 0 ? ib0 : (bank == 1 ? ib1 : ib2);
    const float* wrow = ow + (size_t)j * 1024;
    const float* xx = ib + 2048;
    float acc = 0.f;
    #pragma unroll
    for (int cc = 0; cc < 4; ++cc) {
        float4 a = *(const float4*)(wrow + lane * 16 + cc * 4);
        float4 x = *(const float4*)(xx + lane * 16 + cc * 4);
        acc += a.x * x.x + a.y * x.y + a.z * x.z + a.w * x.w;
    }
    #pragma unroll
    for (int off = 32; off; off >>= 1) acc += __shfl_xor(acc, off);
    if (lane == 0) bp[g] = acc + ob[j];
}

// btot[j] = pb[j] + sum_c bp[c] * pw[j*3072+c]
__global__ __launch_bounds__(256) void btot_kern(
    const float* __restrict__ bp, const float* __restrict__ pw,
    const float* __restrict__ pb, float* __restrict__ btot)
{
    int j = blockIdx.x * 4 + (threadIdx.x >> 6);
    int lane = threadIdx.x & 63;
    const float* row = pw + (size_t)j * 3072;
    float acc = 0.f;
    #pragma unroll
    for (int it = 0; it < 12; ++it) {
        int c = lane * 4 + it * 256;
        float4 a = *(const float4*)(row + c);
        float4 x = *(const float4*)(bp + c);
        acc += a.x * x.x + a.y * x.y + a.z * x.z + a.w * x.w;
    }
    #pragma unroll
    for (int off = 32; off; off >>= 1) acc += __shfl_xor(acc, off);
    if (lane == 0) btot[j] = acc + pb[j];
}

// bqcat2[0:1024]=a, [1024:2048]=b
__global__ __launch_bounds__(256) void gather2(const float* __restrict__ a,
                                               const float* __restrict__ b,
                                               float* __restrict__ o)
{
    int i = blockIdx.x * 256 + threadIdx.x;
    if (i < 1024) o[i] = a[i];
    else if (i < 2048) o[i] = b[i - 1024];
}

// working bank kh/vh
__global__ __launch_bounds__(256) void khvw_kern(
    const float* __restrict__ wm, const float* __restrict__ inw,
    const float* __restrict__ inb, bf* __restrict__ khw, bf* __restrict__ vhw)
{
    int o = blockIdx.x * 4 + (threadIdx.x >> 6); // 0..20479
    int lane = threadIdx.x & 63;
    int sel = o >= 10240;
    int o2 = o - sel * 10240;
    int m = o2 >> 10, c = o2 & 1023;
    const float* wrow = inw + (size_t)(1024 + sel * 1024 + c) * 1024;
    const float* xrow = wm + (size_t)m * 1024;
    float acc = 0.f;
    #pragma unroll
    for (int cc = 0; cc < 4; ++cc) {
        float4 a = *(const float4*)(wrow + lane * 16 + cc * 4);
        float4 x = *(const float4*)(xrow + lane * 16 + cc * 4);
        acc += a.x * x.x + a.y * x.y + a.z * x.z + a.w * x.w;
    }
    #pragma unroll
    for (int off = 32; off; off >>= 1) acc += __shfl_xor(acc, off);
    if (lane == 0) {
        float v = acc + (sel ? 0.f : inb[1024 + c]);
        (sel ? vhw : khw)[(size_t)m * 1024 + c] = __float2bfloat16(v);
    }
}

// ---------------------------------------------------------------------------
extern "C" void kernel_launch(void* const* d_in, const int* in_sizes, int n_in,
                              void* d_out, int out_size, void* d_ws, size_t ws_size,
                              hipStream_t stream)
{
    const float* q     = (const float*)d_in[0];
    const float* data  = (const float*)d_in[1];
    const float* epk   = (const float*)d_in[2];
    const float* epv   = (const float*)d_in[3];
    const float* smk   = (const float*)d_in[4];
    const float* smv   = (const float*)d_in[5];
    const float* wm    = (const float*)d_in[6];
    const float* inw_e = (const float*)d_in[7];  const float* inb_e = (const float*)d_in[8];
    const float* ow_e  = (const float*)d_in[9];  const float* ob_e  = (const float*)d_in[10];
    const float* inw_s = (const float*)d_in[11]; const float* inb_s = (const float*)d_in[12];
    const float* ow_s  = (const float*)d_in[13]; const float* ob_s  = (const float*)d_in[14];
    const float* inw_w = (const float*)d_in[15]; const float* inb_w = (const float*)d_in[16];
    const float* ow_w  = (const float*)d_in[17]; const float* ob_w  = (const float*)d_in[18];
    const float* pw    = (const float*)d_in[19]; const float* pb    = (const float*)d_in[20];
    float* out = (float*)d_out;
    float* part = (float*)d_out;        // split-K partials (phases 1-2)
    bf* qcat2 = (bf*)d_out;             // [8192,2048] q-heads e|s (phase 3a)
    bf* qhw   = (bf*)d_out;             // [8192,1024] q-heads w (phase 3b)

    char* p = (char*)d_ws;
    auto alloc = [&](size_t bytes) -> char* {
        char* r = p; p += (bytes + 255) & ~(size_t)255; return r;
    };
    float* S1     = (float*)alloc(1024 * 256 * 4);
    float* wrT    = (float*)alloc(1024 * 256 * 4);
    float* u      = (float*)alloc(256 * 4);
    float* bp     = (float*)alloc(3072 * 4);
    float* btot   = (float*)alloc(1024 * 4);
    float* bqcat2 = (float*)alloc(2048 * 4);
    bf* wT     = (bf*)alloc(256 * 1024 * 2);
    bf* dT     = (bf*)alloc((size_t)1024 * 1024 * 2);
    bf* epkb   = (bf*)alloc(256 * 1024 * 2);
    bf* smvb   = (bf*)alloc(256 * 1024 * 2);
    bf* ek     = (bf*)alloc(256 * 1024 * 2);
    bf* ev     = (bf*)alloc(256 * 1024 * 2);
    bf* khE    = (bf*)alloc(256 * 1024 * 2);
    bf* khS    = (bf*)alloc(256 * 1024 * 2);
    bf* vTE    = (bf*)alloc((size_t)1024 * 256 * 2);
    bf* vTS    = (bf*)alloc((size_t)1024 * 256 * 2);
    bf* khw    = (bf*)alloc(10 * 1024 * 2);
    bf* vhw    = (bf*)alloc(10 * 1024 * 2);
    bf* Wqcat2 = (bf*)alloc((size_t)2048 * 1024 * 2); // [e_q; s_q]
    bf* WqW    = (bf*)alloc((size_t)1024 * 1024 * 2);
    bf* WkE    = (bf*)alloc((size_t)1024 * 1024 * 2);
    bf* WkS    = (bf*)alloc((size_t)1024 * 1024 * 2);
    bf* owT    = (bf*)alloc((size_t)1024 * 1024 * 2); // reused per bank
    bf* Gcat   = (bf*)alloc((size_t)1024 * 3072 * 2); // [1024, 3072]
    bf* Ocat   = (bf*)alloc((size_t)8192 * 3072 * 2); // attn outputs e|s|w
    if ((size_t)(p - (char*)d_ws) > ws_size) return;

    // ---- phase 0: conversions & bias folds ----
    cvt_f2b<<<256, 256, 0, stream>>>(epk, epkb, 256 * 1024);
    cvt_f2b<<<256, 256, 0, stream>>>(smv, smvb, 256 * 1024);
    cvt_f2b<<<1024, 256, 0, stream>>>(inw_e, Wqcat2, 1024 * 1024);
    cvt_f2b<<<1024, 256, 0, stream>>>(inw_s, (bf*)Wqcat2 + (size_t)1024 * 1024, 1024 * 1024);
    cvt_f2b<<<1024, 256, 0, stream>>>(inw_w, WqW, 1024 * 1024);
    cvt_f2b<<<1024, 256, 0, stream>>>(inw_e + (size_t)1024 * 1024, WkE, 1024 * 1024);
    cvt_f2b<<<1024, 256, 0, stream>>>(inw_s + (size_t)1024 * 1024, WkS, 1024 * 1024);
    transpose_cvt<<<256, 256, 0, stream>>>(data, dT);
    bprime_kern<<<768, 256, 0, stream>>>(ow_e, ob_e, inb_e, ow_s, ob_s, inb_s, ow_w, ob_w, inb_w, bp);
    btot_kern<<<256, 256, 0, stream>>>(bp, pw, pb, btot);
    gather2<<<8, 256, 0, stream>>>(inb_e, inb_s, bqcat2);

    // ---- phase 1: write phase (split-K partials in d_out) ----
    gemm_bt<float, false, true, true, false><<<dim3(16, 8), 256, 0, stream>>>(
        data, 1024, epkb, 1024, nullptr, part, 256, 1024, 256, 1024);
    reduce_sk<float, false><<<256, 256, 0, stream>>>(part, nullptr, S1, 1024 * 256, 256, 256, 8);
    write_softmax<<<1024, 256, 0, stream>>>(S1, wT);
    usum_kern<<<64, 256, 0, stream>>>(wT, u);
    gemm_bt<float, false, true, false, false><<<dim3(16, 8), 256, 0, stream>>>(
        dT, 1024, wT, 1024, nullptr, part, 256, 1024, 256, 1024);
    reduce_sk<float, false><<<256, 256, 0, stream>>>(part, nullptr, wrT, 1024 * 256, 256, 256, 8);
    update_mem<<<1024, 256, 0, stream>>>(epk, epv, u, wrT, ek, ev);

    // ---- phase 2: memory-bank projections + Gcat (partials still in d_out) ----
    gemm_bt<float, false, true, false, false><<<dim3(16, 8), 256, 0, stream>>>(
        ek, 1024, WkE, 1024, nullptr, part, 1024, 256, 1024, 1024);
    reduce_sk<bf, true><<<256, 256, 0, stream>>>(part, inb_e + 1024, khE, 256 * 1024, 1024, 1024, 8);
    gemm_bt<float, false, true, true, false><<<dim3(16, 8), 256, 0, stream>>>(
        inw_e + (size_t)2048 * 1024, 1024, ev, 1024, nullptr, part, 256, 1024, 256, 1024);
    reduce_sk<bf, false><<<256, 256, 0, stream>>>(part, nullptr, vTE, 1024 * 256, 256, 256, 8);
    gemm_bt<float, false, true, true, false><<<dim3(16, 8), 256, 0, stream>>>(
        smk, 1024, WkS, 1024, nullptr, part, 1024, 256, 1024, 1024);
    reduce_sk<bf, true><<<256, 256, 0, stream>>>(part, inb_s + 1024, khS, 256 * 1024, 1024, 1024, 8);
    gemm_bt<float, false, true, true, false><<<dim3(16, 8), 256, 0, stream>>>(
        inw_s + (size_t)2048 * 1024, 1024, smvb, 1024, nullptr, part, 256, 1024, 256, 1024);
    reduce_sk<bf, false><<<256, 256, 0, stream>>>(part, nullptr, vTS, 1024 * 256, 256, 256, 8);
    khvw_kern<<<5120, 256, 0, stream>>>(wm, inw_w, inb_w, khw, vhw);

    const float* ows[3] = {ow_e, ow_s, ow_w};
    for (int b = 0; b < 3; ++b) {
        transpose_cvt<<<256, 256, 0, stream>>>(ows[b], owT);
        gemm_bt<float, false, true, true, false><<<dim3(64, 8), 256, 0, stream>>>(
            pw + b * 1024, 3072, owT, 1024, nullptr, part, 1024, 1024, 1024, 1024);
        reduce_sk<bf, false><<<1024, 256, 0, stream>>>(
            part, nullptr, Gcat + b * 1024, 1024 * 1024, 1024, 3072, 8);
    }

    // ---- phase 3: q-projections (into d_out), attentions, fused out GEMM ----
    // e+s fused q-proj: qcat2[8192,2048] = q @ [Wq_e; Wq_s]^T + bqcat2
    gemm_bt<bf, false, false, true, true><<<1024, 256, 0, stream>>>(
        q, 1024, Wqcat2, 1024, bqcat2, qcat2, 2048, 8192, 2048, 1024);
    attn_mfma2<<<1024, 512, 0, stream>>>(qcat2, 2048, khE, vTE, Ocat + 0, 3072);
    attn_mfma2<<<1024, 512, 0, stream>>>(qcat2 + 1024, 2048, khS, vTS, Ocat + 1024, 3072);
    // w q-proj into d_out (qcat2 dead now)
    gemm_bt<bf, false, false, true, true><<<512, 256, 0, stream>>>(
        q, 1024, WqW, 1024, inb_w, qhw, 1024, 8192, 1024, 1024);
    attn_w<<<8192, 256, 0, stream>>>(qhw, 1024, khw, vhw, Ocat + 2048, 3072);
    // single fused tail: out = Ocat @ Gcat^T + btot
    gemm_bt<float, false, false, false, true><<<512, 256, 0, stream>>>(
        Ocat, 3072, Gcat, 3072, btot, out, 1024, 8192, 1024, 3072);
}

// Round 5
// 330.023 us; speedup vs baseline: 1.9625x; 1.2826x over previous
//
#include <hip/hip_runtime.h>
#include <hip/hip_bf16.h>

// NeuroMemory (f32 I/O). Pipeline: fused cvt/transpose prep; write-phase
// (split-K GEMM -> fused reduce+softmax -> fused reduce+update); ONE grouped
// GEMM for {khE,khS,vTE,vTS,G0,G1,G2} (split-K partials exactly fill d_out) +
// one grouped reduce; 8-wave 128x128 GEMMs for q-projs and the fused tail
// out = Ocat[8192,3072] @ Gcat^T + btot. LDS-staged MFMA attention.

using bf = __hip_bfloat16;
using short8v = __attribute__((ext_vector_type(8))) short;
using f32x4  = __attribute__((ext_vector_type(4))) float;

#define GLOAD_LDS16(g, l) __builtin_amdgcn_global_load_lds( \
    (const __attribute__((address_space(1))) void*)(g), \
    (__attribute__((address_space(3))) void*)(l), 16, 0, 0)

__device__ inline float bf2f(unsigned short s) {
    union { unsigned u; float f; } c; c.u = ((unsigned)s) << 16; return c.f;
}
__device__ inline unsigned short f2bu(float x) { // RNE f32->bf16 bits
    union { float f; unsigned u; } c; c.f = x;
    unsigned r = c.u + 0x7FFF + ((c.u >> 16) & 1);
    return (unsigned short)(r >> 16);
}
__device__ inline void storeC(float* p, float v) { *p = v; }
__device__ inline void storeC(bf* p, float v) { *p = __float2bfloat16(v); }

// ---------------------------------------------------------------------------
// 4-wave 128x128 GEMM (phase-1 split-K only): C = A[M,K] @ B[N,K]^T, partials.
// ---------------------------------------------------------------------------
template <bool AF32>
__global__ __launch_bounds__(256) void gemm_bt(
    const void* __restrict__ Av, int lda,
    const bf* __restrict__ B, int ldb,
    float* __restrict__ part, int M, int N, int K)
{
    __shared__ short As[128 * 64];
    __shared__ short Bs[128 * 64];
    const int nbn = N >> 7;
    const int bm = blockIdx.x / nbn, bn = blockIdx.x % nbn;
    const int t = threadIdx.x;
    const int w = t >> 6, lane = t & 63;
    const int wr = w >> 1, wc = w & 1;
    const int l16 = lane & 15, lhi = lane >> 4;
    const int kc = K / gridDim.y;
    const int kbeg = blockIdx.y * kc, kend = kbeg + kc;

    f32x4 acc[4][4];
    #pragma unroll
    for (int i = 0; i < 4; ++i)
        #pragma unroll
        for (int j = 0; j < 4; ++j) { f32x4 z = {0.f, 0.f, 0.f, 0.f}; acc[i][j] = z; }

    const bf*    Arow  = (const bf*)Av + (size_t)bm * 128 * lda;
    const float* Afrow = (const float*)Av + (size_t)bm * 128 * lda;
    const bf*    Brow  = B + (size_t)bn * 128 * ldb;

    for (int k0 = kbeg; k0 < kend; k0 += 64) {
        #pragma unroll
        for (int j = 0; j < 4; ++j) {
            int u = (w * 4 + j) * 64 + lane;
            int row = u >> 3, c8 = u & 7;
            int slot = c8 ^ (row & 7);
            GLOAD_LDS16(Brow + (size_t)row * ldb + k0 + slot * 8, &Bs[(w * 4 + j) * 512]);
            if (!AF32)
                GLOAD_LDS16(Arow + (size_t)row * lda + k0 + slot * 8, &As[(w * 4 + j) * 512]);
        }
        if (AF32) {
            #pragma unroll
            for (int r = 0; r < 4; ++r) {
                int u = t + (r << 8);
                int row = u >> 3, c8 = u & 7;
                const float* src = Afrow + (size_t)row * lda + k0 + c8 * 8;
                float4 v0 = *(const float4*)src;
                float4 v1 = *(const float4*)(src + 4);
                short8v sv;
                sv[0] = (short)f2bu(v0.x); sv[1] = (short)f2bu(v0.y);
                sv[2] = (short)f2bu(v0.z); sv[3] = (short)f2bu(v0.w);
                sv[4] = (short)f2bu(v1.x); sv[5] = (short)f2bu(v1.y);
                sv[6] = (short)f2bu(v1.z); sv[7] = (short)f2bu(v1.w);
                *(short8v*)&As[row * 64 + ((c8 ^ (row & 7)) * 8)] = sv;
            }
        }
        __syncthreads();
        #pragma unroll
        for (int kk = 0; kk < 2; ++kk) {
            short8v af[4], bfr[4];
            #pragma unroll
            for (int mt = 0; mt < 4; ++mt) {
                int row = wr * 64 + mt * 16 + l16;
                int slot = (kk * 4 + lhi) ^ (row & 7);
                af[mt] = *(const short8v*)&As[row * 64 + slot * 8];
            }
            #pragma unroll
            for (int nt = 0; nt < 4; ++nt) {
                int row = wc * 64 + nt * 16 + l16;
                int slot = (kk * 4 + lhi) ^ (row & 7);
                bfr[nt] = *(const short8v*)&Bs[row * 64 + slot * 8];
            }
            #pragma unroll
            for (int mt = 0; mt < 4; ++mt)
                #pragma unroll
                for (int nt = 0; nt < 4; ++nt)
                    acc[mt][nt] = __builtin_amdgcn_mfma_f32_16x16x32_bf16(
                        af[mt], bfr[nt], acc[mt][nt], 0, 0, 0);
        }
        __syncthreads();
    }
    #pragma unroll
    for (int mt = 0; mt < 4; ++mt)
        #pragma unroll
        for (int nt = 0; nt < 4; ++nt) {
            int col = bn * 128 + wc * 64 + nt * 16 + l16;
            #pragma unroll
            for (int j = 0; j < 4; ++j) {
                int rowg = bm * 128 + wr * 64 + mt * 16 + lhi * 4 + j;
                part[(size_t)blockIdx.y * M * N + (size_t)rowg * N + col] = acc[mt][nt][j];
            }
        }
}

// ---------------------------------------------------------------------------
// 8-wave 128x128 GEMM (phase-3): C = A @ B^T (+bias). 512 thr, waves 2x4,
// each wave 64x32. Same 32KB LDS -> 2 blocks/CU = 16 waves/CU.
// ---------------------------------------------------------------------------
template <typename CT, bool AF32, bool XSWZ>
__global__ __launch_bounds__(512) void gemm8(
    const void* __restrict__ Av, int lda,
    const bf* __restrict__ B, int ldb,
    const float* __restrict__ bias,
    CT* __restrict__ C, int ldc,
    int M, int N, int K)
{
    __shared__ short As[128 * 64];
    __shared__ short Bs[128 * 64];
    const int nbn = N >> 7;
    int bid = blockIdx.x;
    if (XSWZ) bid = (bid & 7) * (gridDim.x >> 3) + (bid >> 3);
    const int bm = bid / nbn, bn = bid % nbn;
    const int t = threadIdx.x;
    const int w = t >> 6, lane = t & 63;
    const int wr = w >> 2, wc = w & 3;
    const int l16 = lane & 15, lhi = lane >> 4;

    f32x4 acc[4][2];
    #pragma unroll
    for (int i = 0; i < 4; ++i)
        #pragma unroll
        for (int j = 0; j < 2; ++j) { f32x4 z = {0.f, 0.f, 0.f, 0.f}; acc[i][j] = z; }

    const bf*    Arow  = (const bf*)Av + (size_t)bm * 128 * lda;
    const float* Afrow = (const float*)Av + (size_t)bm * 128 * lda;
    const bf*    Brow  = B + (size_t)bn * 128 * ldb;

    for (int k0 = 0; k0 < K; k0 += 64) {
        #pragma unroll
        for (int j = 0; j < 2; ++j) {
            int u = t + (j << 9);
            int row = u >> 3, c8 = u & 7;
            int slot = c8 ^ (row & 7);
            GLOAD_LDS16(Brow + (size_t)row * ldb + k0 + slot * 8, &Bs[(j * 8 + w) * 512]);
            if (!AF32)
                GLOAD_LDS16(Arow + (size_t)row * lda + k0 + slot * 8, &As[(j * 8 + w) * 512]);
        }
        if (AF32) {
            #pragma unroll
            for (int r = 0; r < 2; ++r) {
                int u = t + (r << 9);
                int row = u >> 3, c8 = u & 7;
                const float* src = Afrow + (size_t)row * lda + k0 + c8 * 8;
                float4 v0 = *(const float4*)src;
                float4 v1 = *(const float4*)(src + 4);
                short8v sv;
                sv[0] = (short)f2bu(v0.x); sv[1] = (short)f2bu(v0.y);
                sv[2] = (short)f2bu(v0.z); sv[3] = (short)f2bu(v0.w);
                sv[4] = (short)f2bu(v1.x); sv[5] = (short)f2bu(v1.y);
                sv[6] = (short)f2bu(v1.z); sv[7] = (short)f2bu(v1.w);
                *(short8v*)&As[row * 64 + ((c8 ^ (row & 7)) * 8)] = sv;
            }
        }
        __syncthreads();
        #pragma unroll
        for (int kk = 0; kk < 2; ++kk) {
            short8v af[4], bfr[2];
            #pragma unroll
            for (int mt = 0; mt < 4; ++mt) {
                int row = wr * 64 + mt * 16 + l16;
                int slot = (kk * 4 + lhi) ^ (row & 7);
                af[mt] = *(const short8v*)&As[row * 64 + slot * 8];
            }
            #pragma unroll
            for (int nt = 0; nt < 2; ++nt) {
                int row = wc * 32 + nt * 16 + l16;
                int slot = (kk * 4 + lhi) ^ (row & 7);
                bfr[nt] = *(const short8v*)&Bs[row * 64 + slot * 8];
            }
            #pragma unroll
            for (int mt = 0; mt < 4; ++mt)
                #pragma unroll
                for (int nt = 0; nt < 2; ++nt)
                    acc[mt][nt] = __builtin_amdgcn_mfma_f32_16x16x32_bf16(
                        af[mt], bfr[nt], acc[mt][nt], 0, 0, 0);
        }
        __syncthreads();
    }
    #pragma unroll
    for (int mt = 0; mt < 4; ++mt)
        #pragma unroll
        for (int nt = 0; nt < 2; ++nt) {
            int col = bn * 128 + wc * 32 + nt * 16 + l16;
            float bv = bias ? bias[col] : 0.0f;
            #pragma unroll
            for (int j = 0; j < 4; ++j) {
                int rowg = bm * 128 + wr * 64 + mt * 16 + lhi * 4 + j;
                storeC(&C[(size_t)rowg * ldc + col], acc[mt][nt][j] + bv);
            }
        }
}

// ---------------------------------------------------------------------------
// Grouped GEMM: 7 problems, all K=1024, A=f32 (reg-staged+cvt), B=bf16
// (global_load_lds). Split-K=2 via blockIdx.y; partials to per-group pool.
// ---------------------------------------------------------------------------
struct GG { const float* A; const bf* B; float* part; int lda, ldb, M, N, xoff; };
struct GG7 { GG g[7]; };

__global__ __launch_bounds__(256) void ggemm(GG7 P)
{
    __shared__ short As[128 * 64];
    __shared__ short Bs[128 * 64];
    const int bid = blockIdx.x;
    int gidx = 0;
    #pragma unroll
    for (int i = 1; i < 7; ++i) if (bid >= P.g[i].xoff) gidx = i;
    const GG d = P.g[gidx];
    const int lb = bid - d.xoff;
    const int nbn = d.N >> 7;
    const int bm = lb / nbn, bn = lb % nbn;
    const int t = threadIdx.x;
    const int w = t >> 6, lane = t & 63;
    const int wr = w >> 1, wc = w & 1;
    const int l16 = lane & 15, lhi = lane >> 4;
    const int kbeg = blockIdx.y * 512, kend = kbeg + 512;

    f32x4 acc[4][4];
    #pragma unroll
    for (int i = 0; i < 4; ++i)
        #pragma unroll
        for (int j = 0; j < 4; ++j) { f32x4 z = {0.f, 0.f, 0.f, 0.f}; acc[i][j] = z; }

    const float* Afrow = d.A + (size_t)bm * 128 * d.lda;
    const bf*    Brow  = d.B + (size_t)bn * 128 * d.ldb;

    for (int k0 = kbeg; k0 < kend; k0 += 64) {
        #pragma unroll
        for (int j = 0; j < 4; ++j) {
            int u = (w * 4 + j) * 64 + lane;
            int row = u >> 3, c8 = u & 7;
            int slot = c8 ^ (row & 7);
            GLOAD_LDS16(Brow + (size_t)row * d.ldb + k0 + slot * 8, &Bs[(w * 4 + j) * 512]);
        }
        #pragma unroll
        for (int r = 0; r < 4; ++r) {
            int u = t + (r << 8);
            int row = u >> 3, c8 = u & 7;
            const float* src = Afrow + (size_t)row * d.lda + k0 + c8 * 8;
            float4 v0 = *(const float4*)src;
            float4 v1 = *(const float4*)(src + 4);
            short8v sv;
            sv[0] = (short)f2bu(v0.x); sv[1] = (short)f2bu(v0.y);
            sv[2] = (short)f2bu(v0.z); sv[3] = (short)f2bu(v0.w);
            sv[4] = (short)f2bu(v1.x); sv[5] = (short)f2bu(v1.y);
            sv[6] = (short)f2bu(v1.z); sv[7] = (short)f2bu(v1.w);
            *(short8v*)&As[row * 64 + ((c8 ^ (row & 7)) * 8)] = sv;
        }
        __syncthreads();
        #pragma unroll
        for (int kk = 0; kk < 2; ++kk) {
            short8v af[4], bfr[4];
            #pragma unroll
            for (int mt = 0; mt < 4; ++mt) {
                int row = wr * 64 + mt * 16 + l16;
                int slot = (kk * 4 + lhi) ^ (row & 7);
                af[mt] = *(const short8v*)&As[row * 64 + slot * 8];
            }
            #pragma unroll
            for (int nt = 0; nt < 4; ++nt) {
                int row = wc * 64 + nt * 16 + l16;
                int slot = (kk * 4 + lhi) ^ (row & 7);
                bfr[nt] = *(const short8v*)&Bs[row * 64 + slot * 8];
            }
            #pragma unroll
            for (int mt = 0; mt < 4; ++mt)
                #pragma unroll
                for (int nt = 0; nt < 4; ++nt)
                    acc[mt][nt] = __builtin_amdgcn_mfma_f32_16x16x32_bf16(
                        af[mt], bfr[nt], acc[mt][nt], 0, 0, 0);
        }
        __syncthreads();
    }
    #pragma unroll
    for (int mt = 0; mt < 4; ++mt)
        #pragma unroll
        for (int nt = 0; nt < 4; ++nt) {
            int col = bn * 128 + wc * 64 + nt * 16 + l16;
            #pragma unroll
            for (int j = 0; j < 4; ++j) {
                int rowg = bm * 128 + wr * 64 + mt * 16 + lhi * 4 + j;
                d.part[(size_t)blockIdx.y * d.M * d.N + (size_t)rowg * d.N + col]
                    = acc[mt][nt][j];
            }
        }
}

// grouped reduce of split-K=2 partials -> bf16 (+optional bias), strided out
struct GR { const float* part; const float* bias; bf* out; int MN, N, ldo, voff; };
struct GR7 { GR r[7]; };

__global__ __launch_bounds__(256) void gred(GR7 P)
{
    int gi = blockIdx.x * 256 + threadIdx.x;
    int gidx = 0;
    #pragma unroll
    for (int i = 1; i < 7; ++i) if (gi >= P.r[i].voff) gidx = i;
    const GR d = P.r[gidx];
    int i = (gi - d.voff) * 4;
    if (i >= d.MN) return;
    float4 a = *(const float4*)(d.part + i);
    float4 b = *(const float4*)(d.part + d.MN + i);
    a.x += b.x; a.y += b.y; a.z += b.z; a.w += b.w;
    int row = i / d.N, col = i - row * d.N;
    if (d.bias) {
        a.x += d.bias[col]; a.y += d.bias[col + 1];
        a.z += d.bias[col + 2]; a.w += d.bias[col + 3];
    }
    bf* o = d.out + (size_t)row * d.ldo + col;
    ushort4 v;
    v.x = f2bu(a.x); v.y = f2bu(a.y); v.z = f2bu(a.z); v.w = f2bu(a.w);
    *(ushort4*)o = v;
}

// ---------------------------------------------------------------------------
// Attention e/s banks: heads=16, d=64, M=256. 1024 blocks x 512 thr.
// ---------------------------------------------------------------------------
__global__ __launch_bounds__(512) void attn_mfma2(
    const bf* __restrict__ qh, int ldq, const bf* __restrict__ kh,
    const bf* __restrict__ vhT, bf* __restrict__ O, int ldo)
{
    __shared__ short Ks[256 * 64];  // reused as P after QK barrier
    __shared__ short Vs[64 * 256];
    const int qt = blockIdx.x >> 4, head = blockIdx.x & 15;
    const int t = threadIdx.x, w = t >> 6, lane = t & 63;
    const int l16 = lane & 15, lhi = lane >> 4;
    const float scale = 0.125f;

    #pragma unroll
    for (int j = 0; j < 4; ++j) {
        int ublk = w * 4 + j;
        int u = ublk * 64 + lane;
        { int row = u >> 3, c8 = u & 7;
          int slot = c8 ^ (row & 7);
          GLOAD_LDS16(kh + (size_t)row * 1024 + head * 64 + slot * 8, &Ks[ublk * 512]); }
        { int row = u >> 5, c16 = u & 31;
          int slot = c16 ^ (row & 7);
          GLOAD_LDS16(vhT + (size_t)(head * 64 + row) * 256 + slot * 8, &Vs[ublk * 512]); }
    }
    const int qr = qt * 128 + w * 16 + l16;
    short8v aq0 = *(const short8v*)(qh + (size_t)qr * ldq + head * 64 + lhi * 8);
    short8v aq1 = *(const short8v*)(qh + (size_t)qr * ldq + head * 64 + 32 + lhi * 8);
    __syncthreads();

    f32x4 sc[16];
    #pragma unroll
    for (int nt = 0; nt < 16; ++nt) { f32x4 z = {0.f, 0.f, 0.f, 0.f}; sc[nt] = z; }
    #pragma unroll
    for (int nt = 0; nt < 16; ++nt) {
        int row = nt * 16 + l16;
        #pragma unroll
        for (int kk = 0; kk < 2; ++kk) {
            int slot = (kk * 4 + lhi) ^ (row & 7);
            short8v b = *(const short8v*)&Ks[row * 64 + slot * 8];
            sc[nt] = __builtin_amdgcn_mfma_f32_16x16x32_bf16(kk ? aq1 : aq0, b, sc[nt], 0, 0, 0);
        }
    }
    float inv[4];
    #pragma unroll
    for (int j = 0; j < 4; ++j) {
        float m_ = -1e30f;
        #pragma unroll
        for (int nt = 0; nt < 16; ++nt) m_ = fmaxf(m_, sc[nt][j]);
        #pragma unroll
        for (int off = 8; off; off >>= 1) m_ = fmaxf(m_, __shfl_xor(m_, off));
        float s_ = 0.f;
        #pragma unroll
        for (int nt = 0; nt < 16; ++nt) {
            float e = __expf((sc[nt][j] - m_) * scale);
            sc[nt][j] = e; s_ += e;
        }
        #pragma unroll
        for (int off = 8; off; off >>= 1) s_ += __shfl_xor(s_, off);
        inv[j] = 1.0f / s_;
    }
    __syncthreads();

    char* Pw = (char*)Ks + w * 4096;
    f32x4 oa[4];
    #pragma unroll
    for (int nt = 0; nt < 4; ++nt) { f32x4 z = {0.f, 0.f, 0.f, 0.f}; oa[nt] = z; }
    #pragma unroll
    for (int h = 0; h < 2; ++h) {
        #pragma unroll
        for (int nt = 0; nt < 8; ++nt) {
            int colL = nt * 16 + l16;
            #pragma unroll
            for (int j = 0; j < 4; ++j) {
                int row = lhi * 4 + j;
                *(short*)(Pw + row * 256 + ((colL * 2) ^ ((row & 7) << 4)))
                    = (short)f2bu(sc[h * 8 + nt][j] * inv[j]);
            }
        }
        #pragma unroll
        for (int kk = 0; kk < 4; ++kk) {
            short8v a = *(const short8v*)(Pw + l16 * 256 + (((kk * 32 + lhi * 8) * 2) ^ ((l16 & 7) << 4)));
            #pragma unroll
            for (int nt = 0; nt < 4; ++nt) {
                int row = nt * 16 + l16;
                int m = h * 128 + kk * 32 + lhi * 8;
                short8v b = *(const short8v*)((const char*)Vs + row * 512 + ((m * 2) ^ ((row & 7) << 4)));
                oa[nt] = __builtin_amdgcn_mfma_f32_16x16x32_bf16(a, b, oa[nt], 0, 0, 0);
            }
        }
    }
    #pragma unroll
    for (int nt = 0; nt < 4; ++nt)
        #pragma unroll
        for (int j = 0; j < 4; ++j)
            O[(size_t)(qt * 128 + w * 16 + lhi * 4 + j) * ldo + head * 64 + nt * 16 + l16]
                = __float2bfloat16(oa[nt][j]);
}

// ---------------------------------------------------------------------------
// Working-memory attention: heads=8, d=128, M=10.
// ---------------------------------------------------------------------------
__global__ __launch_bounds__(256) void attn_w(
    const bf* __restrict__ qh, int ldq, const bf* __restrict__ khw,
    const bf* __restrict__ vhw, bf* __restrict__ O, int ldo)
{
    const int bs = blockIdx.x;
    const int t = threadIdx.x;
    const int head = t >> 5;
    const int dg = head * 128 + (t & 31) * 4;

    ushort4 qv = *(const ushort4*)(qh + (size_t)bs * ldq + dg);
    float q0 = bf2f(qv.x), q1 = bf2f(qv.y), q2 = bf2f(qv.z), q3 = bf2f(qv.w);
    float s[10];
    #pragma unroll
    for (int m = 0; m < 10; ++m) {
        ushort4 kv = *(const ushort4*)(khw + (size_t)m * 1024 + dg);
        float pr = q0 * bf2f(kv.x) + q1 * bf2f(kv.y) + q2 * bf2f(kv.z) + q3 * bf2f(kv.w);
        #pragma unroll
        for (int off = 16; off; off >>= 1) pr += __shfl_xor(pr, off);
        s[m] = pr * 0.08838834764831845f;
    }
    float mx = s[0];
    #pragma unroll
    for (int m = 1; m < 10; ++m) mx = fmaxf(mx, s[m]);
    float pp[10], sum = 0.f;
    #pragma unroll
    for (int m = 0; m < 10; ++m) { pp[m] = __expf(s[m] - mx); sum += pp[m]; }
    float inv = 1.0f / sum;
    float o0 = 0, o1 = 0, o2 = 0, o3 = 0;
    #pragma unroll
    for (int m = 0; m < 10; ++m) {
        ushort4 vv = *(const ushort4*)(vhw + (size_t)m * 1024 + dg);
        o0 += pp[m] * bf2f(vv.x); o1 += pp[m] * bf2f(vv.y);
        o2 += pp[m] * bf2f(vv.z); o3 += pp[m] * bf2f(vv.w);
    }
    bf* op = O + (size_t)bs * ldo + dg;
    op[0] = __float2bfloat16(o0 * inv); op[1] = __float2bfloat16(o1 * inv);
    op[2] = __float2bfloat16(o2 * inv); op[3] = __float2bfloat16(o3 * inv);
}

// --------------------------- fused prep kernels ----------------------------

// 7-segment f32->bf16 convert (vec4 units, exact total)
struct CS { const float* src; bf* dst; int voff; };
struct CS7 { CS s[7]; };
__global__ __launch_bounds__(256) void cvt_all(CS7 P)
{
    int gi = blockIdx.x * 256 + threadIdx.x;
    int gidx = 0;
    #pragma unroll
    for (int i = 1; i < 7; ++i) if (gi >= P.s[i].voff) gidx = i;
    int i = (gi - P.s[gidx].voff) * 4;
    float4 v = *(const float4*)(P.s[gidx].src + i);
    ushort4 o;
    o.x = f2bu(v.x); o.y = f2bu(v.y); o.z = f2bu(v.z); o.w = f2bu(v.w);
    *(ushort4*)((unsigned short*)P.s[gidx].dst + i) = o;
}

// 4x 1024x1024 f32 -> bf16 transpose (256 blocks each)
__global__ __launch_bounds__(256) void transpose_all(
    const float* s0, bf* d0, const float* s1, bf* d1,
    const float* s2, bf* d2, const float* s3, bf* d3)
{
    __shared__ unsigned short tile[64][65];
    int sel = blockIdx.x >> 8, bb = blockIdx.x & 255;
    const float* in = sel == 0 ? s0 : (sel == 1 ? s1 : (sel == 2 ? s2 : s3));
    bf* outT = sel == 0 ? d0 : (sel == 1 ? d1 : (sel == 2 ? d2 : d3));
    int bx = bb & 15, by = bb >> 4;
    int r0 = by * 64, c0 = bx * 64;
    int tr = threadIdx.x >> 4, tc4 = (threadIdx.x & 15) * 4;
    #pragma unroll
    for (int i = 0; i < 4; ++i) {
        int r = tr + i * 16;
        float4 v = *(const float4*)(in + (size_t)(r0 + r) * 1024 + c0 + tc4);
        tile[r][tc4 + 0] = f2bu(v.x); tile[r][tc4 + 1] = f2bu(v.y);
        tile[r][tc4 + 2] = f2bu(v.z); tile[r][tc4 + 3] = f2bu(v.w);
    }
    __syncthreads();
    #pragma unroll
    for (int i = 0; i < 4; ++i) {
        int r = tr + i * 16;
        ushort4 v;
        v.x = tile[tc4 + 0][r]; v.y = tile[tc4 + 1][r];
        v.z = tile[tc4 + 2][r]; v.w = tile[tc4 + 3][r];
        *(ushort4*)((unsigned short*)outT + (size_t)(c0 + r) * 1024 + r0 + tc4) = v;
    }
}

// reduce 8 S1 partials + softmax + x0.1 -> wT[m][n] (bf16, transposed)
__global__ __launch_bounds__(256) void write_softmax_p(const float* __restrict__ part,
                                                       bf* __restrict__ wT)
{
    const int n = blockIdx.x, m = threadIdx.x;
    float s = 0.f;
    #pragma unroll
    for (int k = 0; k < 8; ++k) s += part[(size_t)k * 262144 + n * 256 + m];
    float mx = s;
    #pragma unroll
    for (int off = 32; off; off >>= 1) mx = fmaxf(mx, __shfl_xor(mx, off));
    __shared__ float red[4], red2[4];
    int w = threadIdx.x >> 6;
    if ((threadIdx.x & 63) == 0) red[w] = mx;
    __syncthreads();
    mx = fmaxf(fmaxf(red[0], red[1]), fmaxf(red[2], red[3]));
    float e = __expf(s - mx);
    float sm = e;
    #pragma unroll
    for (int off = 32; off; off >>= 1) sm += __shfl_xor(sm, off);
    if ((threadIdx.x & 63) == 0) red2[w] = sm;
    __syncthreads();
    sm = red2[0] + red2[1] + red2[2] + red2[3];
    wT[(size_t)m * 1024 + n] = __float2bfloat16(0.1f * e / sm);
}

__global__ __launch_bounds__(256) void usum_kern(const bf* __restrict__ wT, float* __restrict__ u)
{
    int w = threadIdx.x >> 6, lane = threadIdx.x & 63;
    int m = blockIdx.x * 4 + w;
    const bf* row = wT + (size_t)m * 1024;
    float s = 0.f;
    for (int i = lane; i < 1024; i += 64) s += __bfloat162float(row[i]);
    #pragma unroll
    for (int off = 32; off; off >>= 1) s += __shfl_xor(s, off);
    if (lane == 0) u[m] = s * (1.0f / 1024.0f);
}

// reduce 8 writes-partials [s][m][h] + memory update -> ekf (f32), evb (bf16)
__global__ __launch_bounds__(256) void update_fused(
    const float* __restrict__ epk, const float* __restrict__ epv,
    const float* __restrict__ u, const float* __restrict__ part,
    float* __restrict__ ekf, bf* __restrict__ evb)
{
    int i = blockIdx.x * 256 + threadIdx.x; // [m][h], 262144
    int m = i >> 10;
    float wr = 0.f;
    #pragma unroll
    for (int k = 0; k < 8; ++k) wr += part[(size_t)k * 262144 + i];
    wr *= (1.0f / 1024.0f);
    float f = 1.0f - u[m];
    ekf[i] = epk[i] * f + wr;
    evb[i] = __float2bfloat16(epv[i] * f + wr);
}

// bp[bank*1024+j] = out_b[j] + sum_h out_w[j,h] * in_b[2048+h]
__global__ __launch_bounds__(256) void bprime_kern(
    const float* ow0, const float* ob0, const float* ib0,
    const float* ow1, const float* ob1, const float* ib1,
    const float* ow2, const float* ob2, const float* ib2, float* bp)
{
    int g = blockIdx.x * 4 + (threadIdx.x >> 6);
    int lane = threadIdx.x & 63;
    int bank = g >> 10, j = g & 1023;
    const float* ow = bank == 0 ? ow0 : (bank == 1 ? ow1 : ow2);
    const float* ob = bank == 0 ? ob0 : (bank == 1 ? ob1 : ob2);
    const float* ib = bank == 0 ? ib0 : (bank == 1 ? ib1 : ib2);
    const float* wrow = ow + (size_t)j * 1024;
    const float* xx = ib + 2048;
    float acc = 0.f;
    #pragma unroll
    for (int cc = 0; cc < 4; ++cc) {
        float4 a = *(const float4*)(wrow + lane * 16 + cc * 4);
        float4 x = *(const float4*)(xx + lane * 16 + cc * 4);
        acc += a.x * x.x + a.y * x.y + a.z * x.z + a.w * x.w;
    }
    #pragma unroll
    for (int off = 32; off; off >>= 1) acc += __shfl_xor(acc, off);
    if (lane == 0) bp[g] = acc + ob[j];
}

__global__ __launch_bounds__(256) void btot_kern(
    const float* __restrict__ bp, const float* __restrict__ pw,
    const float* __restrict__ pb, float* __restrict__ btot)
{
    int j = blockIdx.x * 4 + (threadIdx.x >> 6);
    int lane = threadIdx.x & 63;
    const float* row = pw + (size_t)j * 3072;
    float acc = 0.f;
    #pragma unroll
    for (int it = 0; it < 12; ++it) {
        int c = lane * 4 + it * 256;
        float4 a = *(const float4*)(row + c);
        float4 x = *(const float4*)(bp + c);
        acc += a.x * x.x + a.y * x.y + a.z * x.z + a.w * x.w;
    }
    #pragma unroll
    for (int off = 32; off; off >>= 1) acc += __shfl_xor(acc, off);
    if (lane == 0) btot[j] = acc + pb[j];
}

__global__ __launch_bounds__(256) void gather2(const float* __restrict__ a,
                                               const float* __restrict__ b,
                                               float* __restrict__ o)
{
    int i = blockIdx.x * 256 + threadIdx.x;
    if (i < 1024) o[i] = a[i];
    else if (i < 2048) o[i] = b[i - 1024];
}

__global__ __launch_bounds__(256) void khvw_kern(
    const float* __restrict__ wm, const float* __restrict__ inw,
    const float* __restrict__ inb, bf* __restrict__ khw, bf* __restrict__ vhw)
{
    int o = blockIdx.x * 4 + (threadIdx.x >> 6);
    int lane = threadIdx.x & 63;
    int sel = o >= 10240;
    int o2 = o - sel * 10240;
    int m = o2 >> 10, c = o2 & 1023;
    const float* wrow = inw + (size_t)(1024 + sel * 1024 + c) * 1024;
    const float* xrow = wm + (size_t)m * 1024;
    float acc = 0.f;
    #pragma unroll
    for (int cc = 0; cc < 4; ++cc) {
        float4 a = *(const float4*)(wrow + lane * 16 + cc * 4);
        float4 x = *(const float4*)(xrow + lane * 16 + cc * 4);
        acc += a.x * x.x + a.y * x.y + a.z * x.z + a.w * x.w;
    }
    #pragma unroll
    for (int off = 32; off; off >>= 1) acc += __shfl_xor(acc, off);
    if (lane == 0) {
        float v = acc + (sel ? 0.f : inb[1024 + c]);
        (sel ? vhw : khw)[(size_t)m * 1024 + c] = __float2bfloat16(v);
    }
}

// ---------------------------------------------------------------------------
extern "C" void kernel_launch(void* const* d_in, const int* in_sizes, int n_in,
                              void* d_out, int out_size, void* d_ws, size_t ws_size,
                              hipStream_t stream)
{
    const float* q     = (const float*)d_in[0];
    const float* data  = (const float*)d_in[1];
    const float* epk   = (const float*)d_in[2];
    const float* epv   = (const float*)d_in[3];
    const float* smk   = (const float*)d_in[4];
    const float* smv   = (const float*)d_in[5];
    const float* wm    = (const float*)d_in[6];
    const float* inw_e = (const float*)d_in[7];  const float* inb_e = (const float*)d_in[8];
    const float* ow_e  = (const float*)d_in[9];  const float* ob_e  = (const float*)d_in[10];
    const float* inw_s = (const float*)d_in[11]; const float* inb_s = (const float*)d_in[12];
    const float* ow_s  = (const float*)d_in[13]; const float* ob_s  = (const float*)d_in[14];
    const float* inw_w = (const float*)d_in[15]; const float* inb_w = (const float*)d_in[16];
    const float* ow_w  = (const float*)d_in[17]; const float* ob_w  = (const float*)d_in[18];
    const float* pw    = (const float*)d_in[19]; const float* pb    = (const float*)d_in[20];
    float* out  = (float*)d_out;
    float* part = (float*)d_out;   // phase-1/2 partial pool (33.5 MB)
    bf* qcat2 = (bf*)d_out;        // phase-3a q-heads e|s
    bf* qhw   = (bf*)d_out;        // phase-3b q-heads w

    char* p = (char*)d_ws;
    auto alloc = [&](size_t bytes) -> char* {
        char* r = p; p += (bytes + 255) & ~(size_t)255; return r;
    };
    float* u      = (float*)alloc(256 * 4);
    float* bp     = (float*)alloc(3072 * 4);
    float* btot   = (float*)alloc(1024 * 4);
    float* bqcat2 = (float*)alloc(2048 * 4);
    float* ekf    = (float*)alloc((size_t)256 * 1024 * 4);
    bf* wT     = (bf*)alloc(256 * 1024 * 2);
    bf* dT     = (bf*)alloc((size_t)1024 * 1024 * 2);
    bf* epkb   = (bf*)alloc(256 * 1024 * 2);
    bf* smvb   = (bf*)alloc(256 * 1024 * 2);
    bf* evb    = (bf*)alloc(256 * 1024 * 2);
    bf* khE    = (bf*)alloc(256 * 1024 * 2);
    bf* khS    = (bf*)alloc(256 * 1024 * 2);
    bf* vTE    = (bf*)alloc((size_t)1024 * 256 * 2);
    bf* vTS    = (bf*)alloc((size_t)1024 * 256 * 2);
    bf* khw    = (bf*)alloc(10 * 1024 * 2);
    bf* vhw    = (bf*)alloc(10 * 1024 * 2);
    bf* Wqcat2 = (bf*)alloc((size_t)2048 * 1024 * 2);
    bf* WqW    = (bf*)alloc((size_t)1024 * 1024 * 2);
    bf* WkE    = (bf*)alloc((size_t)1024 * 1024 * 2);
    bf* WkS    = (bf*)alloc((size_t)1024 * 1024 * 2);
    bf* owT0   = (bf*)alloc((size_t)1024 * 1024 * 2);
    bf* owT1   = (bf*)alloc((size_t)1024 * 1024 * 2);
    bf* owT2   = (bf*)alloc((size_t)1024 * 1024 * 2);
    bf* Gcat   = (bf*)alloc((size_t)1024 * 3072 * 2);
    bf* Ocat   = (bf*)alloc((size_t)8192 * 3072 * 2);
    if ((size_t)(p - (char*)d_ws) > ws_size) return;

    // ---- phase 0: fused conversions, transposes, bias folds ----
    {
        CS7 P = {{ {epk, epkb, 0}, {smv, smvb, 65536},
                   {inw_e, Wqcat2, 131072},
                   {inw_s, Wqcat2 + (size_t)1024 * 1024, 393216},
                   {inw_w, WqW, 655360},
                   {inw_e + (size_t)1024 * 1024, WkE, 917504},
                   {inw_s + (size_t)1024 * 1024, WkS, 1179648} }};
        cvt_all<<<5632, 256, 0, stream>>>(P);
    }
    transpose_all<<<1024, 256, 0, stream>>>(data, dT, ow_e, owT0, ow_s, owT1, ow_w, owT2);
    bprime_kern<<<768, 256, 0, stream>>>(ow_e, ob_e, inb_e, ow_s, ob_s, inb_s, ow_w, ob_w, inb_w, bp);
    btot_kern<<<256, 256, 0, stream>>>(bp, pw, pb, btot);
    gather2<<<8, 256, 0, stream>>>(inb_e, inb_s, bqcat2);

    // ---- phase 1: write phase ----
    gemm_bt<true><<<dim3(16, 8), 256, 0, stream>>>(data, 1024, epkb, 1024, part, 1024, 256, 1024);
    write_softmax_p<<<1024, 256, 0, stream>>>(part, wT);
    usum_kern<<<64, 256, 0, stream>>>(wT, u);
    // writes[m,h] = sum_n wT[m,n] * dT[h,n]
    gemm_bt<false><<<dim3(16, 8), 256, 0, stream>>>(wT, 1024, dT, 1024, part, 256, 1024, 1024);
    update_fused<<<1024, 256, 0, stream>>>(epk, epv, u, part, ekf, evb);
    khvw_kern<<<5120, 256, 0, stream>>>(wm, inw_w, inb_w, khw, vhw);

    // ---- phase 2: ONE grouped GEMM (7 problems, split-K=2) + grouped reduce
    {
        float* pp = part; // exact 8,388,608 f32 = d_out
        GG7 G = {{
            { ekf,                          WkE,  pp + 0,       1024, 1024,  256, 1024, 0   },
            { smk,                          WkS,  pp + 524288,  1024, 1024,  256, 1024, 16  },
            { inw_e + (size_t)2048 * 1024,  evb,  pp + 1048576, 1024, 1024, 1024,  256, 32  },
            { inw_s + (size_t)2048 * 1024,  smvb, pp + 1572864, 1024, 1024, 1024,  256, 48  },
            { pw + 0,                       owT0, pp + 2097152, 3072, 1024, 1024, 1024, 64  },
            { pw + 1024,                    owT1, pp + 4194304, 3072, 1024, 1024, 1024, 128 },
            { pw + 2048,                    owT2, pp + 6291456, 3072, 1024, 1024, 1024, 192 },
        }};
        ggemm<<<dim3(256, 2), 256, 0, stream>>>(G);
        GR7 R = {{
            { pp + 0,       inb_e + 1024, khE,         262144,  1024, 1024, 0      },
            { pp + 524288,  inb_s + 1024, khS,         262144,  1024, 1024, 65536  },
            { pp + 1048576, nullptr,      vTE,         262144,   256,  256, 131072 },
            { pp + 1572864, nullptr,      vTS,         262144,   256,  256, 196608 },
            { pp + 2097152, nullptr,      Gcat + 0,    1048576, 1024, 3072, 262144 },
            { pp + 4194304, nullptr,      Gcat + 1024, 1048576, 1024, 3072, 524288 },
            { pp + 6291456, nullptr,      Gcat + 2048, 1048576, 1024, 3072, 786432 },
        }};
        gred<<<4096, 256, 0, stream>>>(R);
    }

    // ---- phase 3: q-projections (into d_out), attentions, fused tail ----
    gemm8<bf, true, true><<<1024, 512, 0, stream>>>(
        q, 1024, Wqcat2, 1024, bqcat2, qcat2, 2048, 8192, 2048, 1024);
    attn_mfma2<<<1024, 512, 0, stream>>>(qcat2, 2048, khE, vTE, Ocat + 0, 3072);
    attn_mfma2<<<1024, 512, 0, stream>>>(qcat2 + 1024, 2048, khS, vTS, Ocat + 1024, 3072);
    gemm8<bf, true, true><<<512, 512, 0, stream>>>(
        q, 1024, WqW, 1024, inb_w, qhw, 1024, 8192, 1024, 1024);
    attn_w<<<8192, 256, 0, stream>>>(qhw, 1024, khw, vhw, Ocat + 2048, 3072);
    gemm8<float, false, true><<<512, 512, 0, stream>>>(
        Ocat, 3072, Gcat, 3072, btot, out, 1024, 8192, 1024, 3072);
}